// Round 2
// baseline (192.742 us; speedup 1.0000x reference)
//
#include <hip/hip_runtime.h>
#include <math.h>

#define NEG_SLOPE 0.2f
#define BSHIFT 8            // 256 nodes per bucket
#define MAXBUK 512          // supports N up to 131072

typedef __attribute__((ext_vector_type(8))) short short8;   // 8 bf16 (MFMA A/B frag)
typedef __attribute__((ext_vector_type(4))) float floatx4;  // MFMA C/D frag

static __device__ __forceinline__ float lrelu_exp(float e) {
    e = fmaxf(e, NEG_SLOPE * e);
    return __expf(e);
}

// fp32 -> bf16 (round-to-nearest-even)
static __device__ __forceinline__ short f2bf(float f) {
    union { float f; unsigned u; } v; v.f = f;
    unsigned r = v.u + 0x7FFFu + ((v.u >> 16) & 1u);
    return (short)(r >> 16);
}
// bf16 bits -> fp32 (exact)
static __device__ __forceinline__ float bf2f(unsigned short s) {
    union { float f; unsigned u; } v;
    v.u = ((unsigned)s) << 16;
    return v.f;
}
// packed pair of bf16 -> two fp32 (1 shift / 1 and)
static __device__ __forceinline__ float bfpair_lo(unsigned v) {
    union { float f; unsigned u; } x; x.u = v << 16; return x.f;
}
static __device__ __forceinline__ float bfpair_hi(unsigned v) {
    union { float f; unsigned u; } x; x.u = v & 0xffff0000u; return x.f;
}
// split f into hi+lo bf16 pair (covers ~16 mantissa bits)
static __device__ __forceinline__ void splitbf(float f, short& hi, short& lo) {
    hi = f2bf(f);
    lo = f2bf(f - bf2f((unsigned short)hi));
}

// ================= CSR build: LDS-bucketed partition (no global data atomics) =================
// R11: 391 blocks x 512 threads for hist/partition (was 196x256 -> latency-bound);
// colscan is a carry-loop (any NBLK) writing per-bucket totals; bucket_scan only scans totals.

__global__ __launch_bounds__(512) void k_hist(const int* __restrict__ dst, int E, int CHUNK,
                                              int NBLK, int NBUK, int* __restrict__ blockhist) {
    __shared__ int hist[MAXBUK];
    int t = threadIdx.x, b = blockIdx.x;
    for (int i = t; i < NBUK; i += 512) hist[i] = 0;
    __syncthreads();
    int e0 = b * CHUNK, e1 = e0 + CHUNK; if (e1 > E) e1 = E;
    for (int e = e0 + t; e < e1; e += 512) atomicAdd(&hist[dst[e] >> BSHIFT], 1);
    __syncthreads();
    for (int i = t; i < NBUK; i += 512) blockhist[(size_t)i * NBLK + b] = hist[i];
}

// Per-bucket LOCAL exclusive scan across NBLK block-counts (carry loop), writes bucket total.
__global__ __launch_bounds__(256) void k_colscan(int* __restrict__ blockhist,
                                                 int* __restrict__ btot, int NBLK) {
    int bucket = blockIdx.x, t = threadIdx.x;
    int lane = t & 63, wv = t >> 6;
    __shared__ int wsum[4];
    __shared__ int carry_s;
    if (t == 0) carry_s = 0;
    __syncthreads();
    for (int base = 0; base < NBLK; base += 256) {
        int idx = base + t;
        int v = (idx < NBLK) ? blockhist[(size_t)bucket * NBLK + idx] : 0;
        int s = v;
#pragma unroll
        for (int o = 1; o < 64; o <<= 1) {
            int u = __shfl_up(s, o, 64);
            if (lane >= o) s += u;
        }
        if (lane == 63) wsum[wv] = s;
        __syncthreads();
        int b0 = 0;
#pragma unroll
        for (int w = 0; w < 4; ++w) b0 += (w < wv) ? wsum[w] : 0;
        int excl = s + b0 - v + carry_s;
        if (idx < NBLK) blockhist[(size_t)bucket * NBLK + idx] = excl;
        __syncthreads();
        if (t == 255) carry_s += s + b0;   // chunk total
        __syncthreads();
    }
    if (t == 0) btot[bucket] = carry_s;
}

// Exclusive scan over NBUK bucket totals (NBUK <= 512).
__global__ __launch_bounds__(512) void k_bucket_scan(const int* __restrict__ btot,
                                                     int* __restrict__ bucketbase, int NBUK) {
    __shared__ int sh[512];
    int t = threadIdx.x;
    int v = (t < NBUK) ? btot[t] : 0;
    sh[t] = v;
    __syncthreads();
#pragma unroll
    for (int o = 1; o < 512; o <<= 1) {
        int u = (t >= o) ? sh[t - o] : 0;
        __syncthreads();
        sh[t] += u;
        __syncthreads();
    }
    if (t < NBUK) bucketbase[t] = sh[t] - v;
    if (t == NBUK - 1) bucketbase[NBUK] = sh[t];
}

// packed record: (src << 8) | (dst & 255)   [src < 2^24; bucket id recovers dst high bits]
__global__ __launch_bounds__(512) void k_partition(const int* __restrict__ src,
                                                   const int* __restrict__ dst, int E, int CHUNK,
                                                   int NBLK, int NBUK,
                                                   const int* __restrict__ blockhist,
                                                   const int* __restrict__ bucketbase,
                                                   unsigned* __restrict__ packed) {
    __shared__ int cur[MAXBUK];
    int t = threadIdx.x, b = blockIdx.x;
    for (int i = t; i < NBUK; i += 512)
        cur[i] = blockhist[(size_t)i * NBLK + b] + bucketbase[i];
    __syncthreads();
    int e0 = b * CHUNK, e1 = e0 + CHUNK; if (e1 > E) e1 = E;
    for (int e = e0 + t; e < e1; e += 512) {
        int d = dst[e], s = src[e];
        int pos = atomicAdd(&cur[d >> BSHIFT], 1);
        packed[pos] = ((unsigned)s << 8) | ((unsigned)d & 255u);
    }
}

__global__ __launch_bounds__(256) void k_fine(const unsigned* __restrict__ packed,
                                              const int* __restrict__ bucketbase,
                                              int* __restrict__ offsets,
                                              int* __restrict__ csr_src,
                                              int N, int NBUK) {
    __shared__ int fcnt[256];
    __shared__ int wsum[4];
    int bucket = blockIdx.x, t = threadIdx.x;
    int lo = bucket << BSHIFT;
    int nn = N - lo; if (nn > 256) nn = 256;
    int ebase = bucketbase[bucket];
    int ecnt = bucketbase[bucket + 1] - ebase;
    fcnt[t] = 0;
    __syncthreads();
    for (int i = t; i < ecnt; i += 256) {
        unsigned p = packed[ebase + i];
        atomicAdd(&fcnt[p & 255u], 1);
    }
    __syncthreads();
    int v = fcnt[t];
    int lane = t & 63, wv = t >> 6;
    int s = v;
#pragma unroll
    for (int o = 1; o < 64; o <<= 1) {
        int u = __shfl_up(s, o, 64);
        if (lane >= o) s += u;
    }
    if (lane == 63) wsum[wv] = s;
    __syncthreads();
    int base = 0;
#pragma unroll
    for (int w = 0; w < 4; ++w) base += (w < wv) ? wsum[w] : 0;
    int excl = s + base - v;
    if (t < nn) offsets[lo + t] = ebase + excl;
    if (bucket == NBUK - 1 && t == 0) offsets[N] = ebase + ecnt;  // == E
    __syncthreads();
    fcnt[t] = excl;   // reuse as cursor
    __syncthreads();
    for (int i = t; i < ecnt; i += 256) {
        unsigned p = packed[ebase + i];
        int pos = atomicAdd(&fcnt[p & 255u], 1);
        csr_src[ebase + pos] = (int)(p >> 8);
    }
}

// ---------------- W2 pre-split: hi/lo bf16, padded 40 -> 48 cols ----------------
__global__ __launch_bounds__(256) void k_splitW2(const float* __restrict__ W2,
                                                 short* __restrict__ w2h,
                                                 short* __restrict__ w2l) {
    int i = blockIdx.x * 256 + threadIdx.x;
    if (i < 64 * 48) {
        int row = i / 48, col = i % 48;
        short hi = 0, lo = 0;
        if (col < 40) splitbf(W2[row * 40 + col], hi, lo);
        w2h[i] = hi; w2l[i] = lo;
    }
}

// ---------------- Layer 1 GEMM via MFMA bf16 (plain; inputs replay-constant) ----------------
__global__ __launch_bounds__(256) void k_gemm1(const float* __restrict__ x,
                                               const float* __restrict__ W1,
                                               const float* __restrict__ att_s,
                                               const float* __restrict__ att_d,
                                               unsigned short* __restrict__ h1b,
                                               float* __restrict__ a_s1,
                                               float* __restrict__ a_d1, int N) {
    int tid = threadIdx.x, wave = tid >> 6, lane = tid & 63;
    int n16 = lane & 15, q = lane >> 4;
    int nb = blockIdx.x * 64 + wave * 16;
    if (nb >= N) return;

    short8 bfr[4][4];
#pragma unroll
    for (int ct = 0; ct < 4; ++ct) {
        int n = ct * 16 + n16;
#pragma unroll
        for (int kc = 0; kc < 4; ++kc) {
            int k0 = kc * 32 + q * 8;
            short8 b;
#pragma unroll
            for (int j = 0; j < 8; ++j) b[j] = f2bf(W1[(k0 + j) * 64 + n]);
            bfr[ct][kc] = b;
        }
    }

    int arow = nb + n16; if (arow >= N) arow = N - 1;
    const float* xr = x + (size_t)arow * 128 + q * 8;
    short8 afr[4];
#pragma unroll
    for (int kc = 0; kc < 4; ++kc) {
        float4 u0 = *(const float4*)(xr + kc * 32);
        float4 u1 = *(const float4*)(xr + kc * 32 + 4);
        short8 a;
        a[0] = f2bf(u0.x); a[1] = f2bf(u0.y); a[2] = f2bf(u0.z); a[3] = f2bf(u0.w);
        a[4] = f2bf(u1.x); a[5] = f2bf(u1.y); a[6] = f2bf(u1.z); a[7] = f2bf(u1.w);
        afr[kc] = a;
    }

    floatx4 acc[4];
#pragma unroll
    for (int ct = 0; ct < 4; ++ct) {
        floatx4 c = {0.f, 0.f, 0.f, 0.f};
#pragma unroll
        for (int kc = 0; kc < 4; ++kc)
            c = __builtin_amdgcn_mfma_f32_16x16x32_bf16(afr[kc], bfr[ct][kc], c, 0, 0, 0);
        acc[ct] = c;
    }

#pragma unroll
    for (int ct = 0; ct < 4; ++ct) {
#pragma unroll
        for (int r = 0; r < 4; ++r) {
            int row = nb + q * 4 + r;
            if (row < N) h1b[(size_t)row * 64 + ct * 16 + n16] = (unsigned short)f2bf(acc[ct][r]);
        }
    }

#pragma unroll
    for (int ct = 0; ct < 4; ++ct) {
        float as = att_s[ct * 16 + n16];
        float ad = att_d[ct * 16 + n16];
#pragma unroll
        for (int r = 0; r < 4; ++r) {
            float ps = acc[ct][r] * as;
            float pd = acc[ct][r] * ad;
#pragma unroll
            for (int m = 1; m < 8; m <<= 1) {
                ps += __shfl_xor(ps, m, 64);
                pd += __shfl_xor(pd, m, 64);
            }
            int row = nb + q * 4 + r;
            if ((n16 & 7) == 0 && row < N) {
                int h = 2 * ct + (n16 >> 3);
                a_s1[row * 8 + h] = ps;
                a_d1[row * 8 + h] = pd;
            }
        }
    }
}

// ---------------- Layer 1 aggregation: R12 head-per-lane scheme ----------------------
// lane = (g, h): g = lane>>3 edge slot (8 edges per step), h = lane&7 head.
__global__ __launch_bounds__(256) void k_agg1(const unsigned short* __restrict__ h1b,
                                              const float* __restrict__ a_s1,
                                              const float* __restrict__ a_d1,
                                              const int* __restrict__ offsets,
                                              const int* __restrict__ csr_src,
                                              const float* __restrict__ b1,
                                              float* __restrict__ y1, int N) {
    int wave = threadIdx.x >> 6, lane = threadIdx.x & 63;
    int d = blockIdx.x * 4 + wave;
    if (d >= N) return;
    int g = lane >> 3;           // edge slot within an 8-edge step
    int h = lane & 7;            // head (channels 8h..8h+7)
    float ad = a_d1[d * 8 + h];
    float acc[8] = {0.f, 0.f, 0.f, 0.f, 0.f, 0.f, 0.f, 0.f};
    float wsum_l = 0.f;
    if (g == 0) {                // self-loop on slot 0
        float w0 = lrelu_exp(a_s1[d * 8 + h] + ad);
        uint4 v = *(const uint4*)(h1b + (size_t)d * 64 + 8 * h);
        acc[0] = w0 * bfpair_lo(v.x); acc[1] = w0 * bfpair_hi(v.x);
        acc[2] = w0 * bfpair_lo(v.y); acc[3] = w0 * bfpair_hi(v.y);
        acc[4] = w0 * bfpair_lo(v.z); acc[5] = w0 * bfpair_hi(v.z);
        acc[6] = w0 * bfpair_lo(v.w); acc[7] = w0 * bfpair_hi(v.w);
        wsum_l = w0;
    }
    int i0 = offsets[d], i1 = offsets[d + 1];
    for (int base = i0; base < i1; base += 64) {
        int m = i1 - base; if (m > 64) m = 64;
        int sv = (lane < m) ? csr_src[base + lane] : 0;
        for (int j = 0; j < m; j += 16) {
            // --- group A: edges j..j+7 (always live since j < m) ---
            int eA = j + g;
            int siA = __shfl(sv, eA, 64);
            bool liveB = (j + 8 < m);
            if (liveB) {
                // --- both groups: batch shfls+loads for ILP ---
                int eB = j + 8 + g;
                int siB = __shfl(sv, eB, 64);
                float evA = a_s1[siA * 8 + h] + ad;
                float evB = a_s1[siB * 8 + h] + ad;
                uint4 vA = *(const uint4*)(h1b + (size_t)siA * 64 + 8 * h);
                uint4 vB = *(const uint4*)(h1b + (size_t)siB * 64 + 8 * h);
                float wA = (eA < m) ? lrelu_exp(evA) : 0.f;
                float wB = (eB < m) ? lrelu_exp(evB) : 0.f;
                wsum_l += wA + wB;
                acc[0] = fmaf(wA, bfpair_lo(vA.x), acc[0]);
                acc[1] = fmaf(wA, bfpair_hi(vA.x), acc[1]);
                acc[2] = fmaf(wA, bfpair_lo(vA.y), acc[2]);
                acc[3] = fmaf(wA, bfpair_hi(vA.y), acc[3]);
                acc[4] = fmaf(wA, bfpair_lo(vA.z), acc[4]);
                acc[5] = fmaf(wA, bfpair_hi(vA.z), acc[5]);
                acc[6] = fmaf(wA, bfpair_lo(vA.w), acc[6]);
                acc[7] = fmaf(wA, bfpair_hi(vA.w), acc[7]);
                acc[0] = fmaf(wB, bfpair_lo(vB.x), acc[0]);
                acc[1] = fmaf(wB, bfpair_hi(vB.x), acc[1]);
                acc[2] = fmaf(wB, bfpair_lo(vB.y), acc[2]);
                acc[3] = fmaf(wB, bfpair_hi(vB.y), acc[3]);
                acc[4] = fmaf(wB, bfpair_lo(vB.z), acc[4]);
                acc[5] = fmaf(wB, bfpair_hi(vB.z), acc[5]);
                acc[6] = fmaf(wB, bfpair_lo(vB.w), acc[6]);
                acc[7] = fmaf(wB, bfpair_hi(vB.w), acc[7]);
            } else {
                float evA = a_s1[siA * 8 + h] + ad;
                uint4 vA = *(const uint4*)(h1b + (size_t)siA * 64 + 8 * h);
                float wA = (eA < m) ? lrelu_exp(evA) : 0.f;
                wsum_l += wA;
                acc[0] = fmaf(wA, bfpair_lo(vA.x), acc[0]);
                acc[1] = fmaf(wA, bfpair_hi(vA.x), acc[1]);
                acc[2] = fmaf(wA, bfpair_lo(vA.y), acc[2]);
                acc[3] = fmaf(wA, bfpair_hi(vA.y), acc[3]);
                acc[4] = fmaf(wA, bfpair_lo(vA.z), acc[4]);
                acc[5] = fmaf(wA, bfpair_hi(vA.z), acc[5]);
                acc[6] = fmaf(wA, bfpair_lo(vA.w), acc[6]);
                acc[7] = fmaf(wA, bfpair_hi(vA.w), acc[7]);
            }
        }
    }
    // reduce across the 8 edge slots (lanes h, h+8, ..., h+56)
#pragma unroll
    for (int mm = 8; mm < 64; mm <<= 1) {
#pragma unroll
        for (int k = 0; k < 8; ++k) acc[k] += __shfl_xor(acc[k], mm, 64);
        wsum_l += __shfl_xor(wsum_l, mm, 64);
    }
    if (g == 0) {
        float inv = 1.f / (wsum_l + 1e-16f);
        float4 bA = *(const float4*)(b1 + 8 * h);
        float4 bB = *(const float4*)(b1 + 8 * h + 4);
        float o[8];
        o[0] = acc[0] * inv + bA.x;
        o[1] = acc[1] * inv + bA.y;
        o[2] = acc[2] * inv + bA.z;
        o[3] = acc[3] * inv + bA.w;
        o[4] = acc[4] * inv + bB.x;
        o[5] = acc[5] * inv + bB.y;
        o[6] = acc[6] * inv + bB.z;
        o[7] = acc[7] * inv + bB.w;
#pragma unroll
        for (int k = 0; k < 8; ++k) o[k] = o[k] > 0.f ? o[k] : (__expf(o[k]) - 1.f);
        float4 s0 = make_float4(o[0], o[1], o[2], o[3]);
        float4 s1 = make_float4(o[4], o[5], o[6], o[7]);
        *(float4*)(y1 + (size_t)d * 64 + 8 * h) = s0;       // fp32 (precision-critical)
        *(float4*)(y1 + (size_t)d * 64 + 8 * h + 4) = s1;
    }
}

// ---------------- Layer 2 GEMM, split-bf16 (y1 replay-variant -> fp32-class needed) ----------
__global__ __launch_bounds__(256) void k_gemm2(const float* __restrict__ y1,
                                               const short* __restrict__ w2h,
                                               const short* __restrict__ w2l,
                                               const float* __restrict__ att_s,
                                               const float* __restrict__ att_d,
                                               unsigned short* __restrict__ h2b,
                                               float* __restrict__ a2s,
                                               float* __restrict__ a2d, int N) {
    int tid = threadIdx.x, wave = tid >> 6, lane = tid & 63;
    int n16 = lane & 15, q = lane >> 4;
    int nb = blockIdx.x * 64 + wave * 16;
    if (nb >= N) return;

    int arow = nb + n16; if (arow >= N) arow = N - 1;
    const float* yr = y1 + (size_t)arow * 64 + q * 8;
    short8 ah[2], al[2];
#pragma unroll
    for (int kc = 0; kc < 2; ++kc) {
        float4 u0 = *(const float4*)(yr + kc * 32);
        float4 u1 = *(const float4*)(yr + kc * 32 + 4);
        short8 h, l; short hi, lo;
        splitbf(u0.x, hi, lo); h[0] = hi; l[0] = lo;
        splitbf(u0.y, hi, lo); h[1] = hi; l[1] = lo;
        splitbf(u0.z, hi, lo); h[2] = hi; l[2] = lo;
        splitbf(u0.w, hi, lo); h[3] = hi; l[3] = lo;
        splitbf(u1.x, hi, lo); h[4] = hi; l[4] = lo;
        splitbf(u1.y, hi, lo); h[5] = hi; l[5] = lo;
        splitbf(u1.z, hi, lo); h[6] = hi; l[6] = lo;
        splitbf(u1.w, hi, lo); h[7] = hi; l[7] = lo;
        ah[kc] = h; al[kc] = l;
    }

    float psr[4] = {0.f, 0.f, 0.f, 0.f}, pdr[4] = {0.f, 0.f, 0.f, 0.f};
#pragma unroll
    for (int ct = 0; ct < 3; ++ct) {
        int n = ct * 16 + n16;
        short8 bh0, bh1, bl0, bl1;
#pragma unroll
        for (int j = 0; j < 8; ++j) {
            int k0 = q * 8 + j;
            bh0[j] = w2h[k0 * 48 + n];
            bl0[j] = w2l[k0 * 48 + n];
            bh1[j] = w2h[(32 + k0) * 48 + n];
            bl1[j] = w2l[(32 + k0) * 48 + n];
        }
        floatx4 c = {0.f, 0.f, 0.f, 0.f};
        c = __builtin_amdgcn_mfma_f32_16x16x32_bf16(ah[0], bl0, c, 0, 0, 0);
        c = __builtin_amdgcn_mfma_f32_16x16x32_bf16(al[0], bh0, c, 0, 0, 0);
        c = __builtin_amdgcn_mfma_f32_16x16x32_bf16(ah[0], bh0, c, 0, 0, 0);
        c = __builtin_amdgcn_mfma_f32_16x16x32_bf16(ah[1], bl1, c, 0, 0, 0);
        c = __builtin_amdgcn_mfma_f32_16x16x32_bf16(al[1], bh1, c, 0, 0, 0);
        c = __builtin_amdgcn_mfma_f32_16x16x32_bf16(ah[1], bh1, c, 0, 0, 0);

        int col = ct * 16 + n16;
#pragma unroll
        for (int r = 0; r < 4; ++r) {
            int row = nb + q * 4 + r;
            if (col < 40 && row < N) h2b[(size_t)row * 40 + col] = (unsigned short)f2bf(c[r]);
        }
        float asv = (col < 40) ? att_s[col] : 0.f;
        float adv = (col < 40) ? att_d[col] : 0.f;
#pragma unroll
        for (int r = 0; r < 4; ++r) {
            psr[r] = fmaf(c[r], asv, psr[r]);
            pdr[r] = fmaf(c[r], adv, pdr[r]);
        }
    }
#pragma unroll
    for (int r = 0; r < 4; ++r) {
        float ps = psr[r], pd = pdr[r];
#pragma unroll
        for (int m = 1; m < 16; m <<= 1) {
            ps += __shfl_xor(ps, m, 64);
            pd += __shfl_xor(pd, m, 64);
        }
        int row = nb + q * 4 + r;
        if (n16 == 0 && row < N) { a2s[row] = ps; a2d[row] = pd; }
    }
}

// ---------------- Layer 2 aggregation: R13 5-lane/edge dwordx4 scheme + log_softmax ----------
// lane = g*5 + c for lane<60: g = edge slot (0..11), c = 16B chunk of the 80B row (c=0..4,
// channels 8c..8c+7). One scattered dwordx4 instr covers 12 edges (was: 1 dword covers 3.2).
// Cross-group (12-way, non-pow2) reduction via 4-shfl fold: +30, +15, +5, +10.
__global__ __launch_bounds__(256) void k_agg2(const unsigned short* __restrict__ h2b,
                                              const float* __restrict__ a2s,
                                              const float* __restrict__ a2d,
                                              const int* __restrict__ offsets,
                                              const int* __restrict__ csr_src,
                                              const float* __restrict__ b2,
                                              float* __restrict__ out, int N) {
    int wave = threadIdx.x >> 6, lane = threadIdx.x & 63;
    int d = blockIdx.x * 4 + wave;
    if (d >= N) return;
    bool act = (lane < 60);
    int g = act ? (lane / 5) : 0;        // edge slot 0..11 (idle lanes alias slot 0)
    int c = act ? (lane - g * 5) : 0;    // 16B chunk 0..4
    float ad = a2d[d];
    float w0 = lrelu_exp(a2s[d] + ad);
    float acc[8] = {0.f, 0.f, 0.f, 0.f, 0.f, 0.f, 0.f, 0.f};
    if (lane < 5) {                      // self-loop handled by group 0 (lanes 0..4)
        uint4 v = *(const uint4*)(h2b + (size_t)d * 40 + 8 * c);
        acc[0] = w0 * bfpair_lo(v.x); acc[1] = w0 * bfpair_hi(v.x);
        acc[2] = w0 * bfpair_lo(v.y); acc[3] = w0 * bfpair_hi(v.y);
        acc[4] = w0 * bfpair_lo(v.z); acc[5] = w0 * bfpair_hi(v.z);
        acc[6] = w0 * bfpair_lo(v.w); acc[7] = w0 * bfpair_hi(v.w);
    }
    float wsum_l = 0.f;
    int i0 = offsets[d], i1 = offsets[d + 1];
    for (int base = i0; base < i1; base += 60) {
        int m = i1 - base; if (m > 60) m = 60;
        int sv = 0; float wv = 0.f;
        if (lane < m) {
            sv = csr_src[base + lane];
            wv = lrelu_exp(a2s[sv] + ad);
        }
        wsum_l += wv;
        for (int j = 0; j < m; j += 24) {
            int eA = j + g;                     // <= 59 always (j<=48, g<=11)
            int siA = __shfl(sv, eA, 64);
            float wqA = __shfl(wv, eA, 64);
            if (!act || eA >= m) wqA = 0.f;
            bool liveB = (j + 12 < m);
            if (liveB) {
                int eB = j + 12 + g;            // <= 59+12? j<=m-13 -> eB<=58  safe
                int siB = __shfl(sv, eB, 64);
                float wqB = __shfl(wv, eB, 64);
                if (!act || eB >= m) wqB = 0.f;
                uint4 vA = *(const uint4*)(h2b + (size_t)siA * 40 + 8 * c);
                uint4 vB = *(const uint4*)(h2b + (size_t)siB * 40 + 8 * c);
                acc[0] = fmaf(wqA, bfpair_lo(vA.x), acc[0]);
                acc[1] = fmaf(wqA, bfpair_hi(vA.x), acc[1]);
                acc[2] = fmaf(wqA, bfpair_lo(vA.y), acc[2]);
                acc[3] = fmaf(wqA, bfpair_hi(vA.y), acc[3]);
                acc[4] = fmaf(wqA, bfpair_lo(vA.z), acc[4]);
                acc[5] = fmaf(wqA, bfpair_hi(vA.z), acc[5]);
                acc[6] = fmaf(wqA, bfpair_lo(vA.w), acc[6]);
                acc[7] = fmaf(wqA, bfpair_hi(vA.w), acc[7]);
                acc[0] = fmaf(wqB, bfpair_lo(vB.x), acc[0]);
                acc[1] = fmaf(wqB, bfpair_hi(vB.x), acc[1]);
                acc[2] = fmaf(wqB, bfpair_lo(vB.y), acc[2]);
                acc[3] = fmaf(wqB, bfpair_hi(vB.y), acc[3]);
                acc[4] = fmaf(wqB, bfpair_lo(vB.z), acc[4]);
                acc[5] = fmaf(wqB, bfpair_hi(vB.z), acc[5]);
                acc[6] = fmaf(wqB, bfpair_lo(vB.w), acc[6]);
                acc[7] = fmaf(wqB, bfpair_hi(vB.w), acc[7]);
            } else {
                uint4 vA = *(const uint4*)(h2b + (size_t)siA * 40 + 8 * c);
                acc[0] = fmaf(wqA, bfpair_lo(vA.x), acc[0]);
                acc[1] = fmaf(wqA, bfpair_hi(vA.x), acc[1]);
                acc[2] = fmaf(wqA, bfpair_lo(vA.y), acc[2]);
                acc[3] = fmaf(wqA, bfpair_hi(vA.y), acc[3]);
                acc[4] = fmaf(wqA, bfpair_lo(vA.z), acc[4]);
                acc[5] = fmaf(wqA, bfpair_hi(vA.z), acc[5]);
                acc[6] = fmaf(wqA, bfpair_lo(vA.w), acc[6]);
                acc[7] = fmaf(wqA, bfpair_hi(vA.w), acc[7]);
            }
        }
    }
    // fold 12 edge-groups into group 0 (lanes 0..4), same c:  +30, +15, then +5 and +10
#pragma unroll
    for (int k = 0; k < 8; ++k) {
        acc[k] += __shfl(acc[k], lane + 30, 64);
        acc[k] += __shfl(acc[k], lane + 15, 64);
        acc[k] += __shfl(acc[k], lane + 5, 64) + __shfl(acc[k], lane + 10, 64);
    }
    // wsum: every edge's weight lives in exactly one lane (lane<m phase) -> full butterfly
#pragma unroll
    for (int mm = 1; mm < 64; mm <<= 1) wsum_l += __shfl_xor(wsum_l, mm, 64);
    float wsum = wsum_l + w0;
    bool act5 = (lane < 5);
    float inv = 1.f / (wsum + 1e-16f);
    float o[8];
    float4 bA = *(const float4*)(b2 + 8 * c);
    float4 bB = *(const float4*)(b2 + 8 * c + 4);
    o[0] = acc[0] * inv + bA.x;
    o[1] = acc[1] * inv + bA.y;
    o[2] = acc[2] * inv + bA.z;
    o[3] = acc[3] * inv + bA.w;
    o[4] = acc[4] * inv + bB.x;
    o[5] = acc[5] * inv + bB.y;
    o[6] = acc[6] * inv + bB.z;
    o[7] = acc[7] * inv + bB.w;
    // log_softmax over 40 channels: lanes 0..4 hold 8 each; 3-step butterfly within 8-lane group
    float mxl = -INFINITY;
    if (act5) {
        mxl = fmaxf(fmaxf(fmaxf(o[0], o[1]), fmaxf(o[2], o[3])),
                    fmaxf(fmaxf(o[4], o[5]), fmaxf(o[6], o[7])));
    }
#pragma unroll
    for (int mm = 1; mm < 8; mm <<= 1) mxl = fmaxf(mxl, __shfl_xor(mxl, mm, 64));
    float exl = 0.f;
    if (act5) {
#pragma unroll
        for (int k = 0; k < 8; ++k) exl += __expf(o[k] - mxl);
    }
#pragma unroll
    for (int mm = 1; mm < 8; mm <<= 1) exl += __shfl_xor(exl, mm, 64);
    if (act5) {
        float lse = mxl + __logf(exl);
        float4 s0 = make_float4(o[0] - lse, o[1] - lse, o[2] - lse, o[3] - lse);
        float4 s1 = make_float4(o[4] - lse, o[5] - lse, o[6] - lse, o[7] - lse);
        *(float4*)(out + (size_t)d * 40 + 8 * c) = s0;
        *(float4*)(out + (size_t)d * 40 + 8 * c + 4) = s1;
    }
}

// ---------------- launcher ----------------

extern "C" void kernel_launch(void* const* d_in, const int* in_sizes, int n_in,
                              void* d_out, int out_size, void* d_ws, size_t ws_size,
                              hipStream_t stream) {
    const float* x   = (const float*)d_in[0];
    const int*   ei  = (const int*)d_in[1];
    const float* W1  = (const float*)d_in[2];
    const float* as1 = (const float*)d_in[3];
    const float* ad1 = (const float*)d_in[4];
    const float* b1  = (const float*)d_in[5];
    const float* W2  = (const float*)d_in[6];
    const float* as2 = (const float*)d_in[7];
    const float* ad2 = (const float*)d_in[8];
    const float* b2  = (const float*)d_in[9];
    float* out = (float*)d_out;

    int N = in_sizes[0] / 128;   // 100000
    int E = in_sizes[1] / 2;     // 1600000
    const int* src = ei;
    const int* dst = ei + E;

    int NBUK = (N + 255) >> BSHIFT;          // 391
    int CHUNK = 4096;
    int NBLK = (E + CHUNK - 1) / CHUNK;      // 391

    char* ws = (char*)d_ws;
    size_t off = 0;
    auto alloc = [&](size_t bytes) -> char* {
        char* p = ws + off;
        off += (bytes + 255) & ~(size_t)255;
        return p;
    };
    unsigned short* h1b = (unsigned short*)alloc((size_t)N * 64 * 2);   // bf16
    float* a_s1    = (float*)alloc((size_t)N * 8 * 4);
    float* a_d1    = (float*)alloc((size_t)N * 8 * 4);
    float* y1      = (float*)alloc((size_t)N * 64 * 4);                 // fp32 (precision-critical)
    // h2b (bf16, 8 MB) and packed (uint, 6.4 MB) are temporally disjoint: share region.
    size_t shared_sz = (size_t)N * 40 * 2;
    if ((size_t)E * 4 > shared_sz) shared_sz = (size_t)E * 4;
    char*  region  = alloc(shared_sz);
    unsigned short* h2b = (unsigned short*)region;
    unsigned* packed    = (unsigned*)region;
    float* a2s     = (float*)alloc((size_t)N * 4);
    float* a2d     = (float*)alloc((size_t)N * 4);
    int*   offsets = (int*)alloc((size_t)(N + 1) * 4);
    int*   csr_src = (int*)alloc((size_t)E * 4);
    int*   blockhist  = (int*)alloc((size_t)NBUK * NBLK * 4);
    int*   btot       = (int*)alloc((size_t)NBUK * 4);
    int*   bucketbase = (int*)alloc((size_t)(NBUK + 1) * 4);
    short* w2h     = (short*)alloc((size_t)64 * 48 * 2);
    short* w2l     = (short*)alloc((size_t)64 * 48 * 2);

    int nb = (N + 3) / 4;
    int gb = (N + 63) / 64;

    k_hist<<<NBLK, 512, 0, stream>>>(dst, E, CHUNK, NBLK, NBUK, blockhist);
    k_colscan<<<NBUK, 256, 0, stream>>>(blockhist, btot, NBLK);
    k_bucket_scan<<<1, 512, 0, stream>>>(btot, bucketbase, NBUK);
    k_partition<<<NBLK, 512, 0, stream>>>(src, dst, E, CHUNK, NBLK, NBUK, blockhist,
                                          bucketbase, packed);
    k_fine<<<NBUK, 256, 0, stream>>>(packed, bucketbase, offsets, csr_src, N, NBUK);
    k_splitW2<<<12, 256, 0, stream>>>(W2, w2h, w2l);
    k_gemm1<<<gb, 256, 0, stream>>>(x, W1, as1, ad1, h1b, a_s1, a_d1, N);
    k_agg1<<<nb, 256, 0, stream>>>(h1b, a_s1, a_d1, offsets, csr_src, b1, y1, N);
    k_gemm2<<<gb, 256, 0, stream>>>(y1, w2h, w2l, as2, ad2, h2b, a2s, a2d, N);
    k_agg2<<<nb, 256, 0, stream>>>(h2b, a2s, a2d, offsets, csr_src, b2, out, N);
}

// Round 3
// 172.628 us; speedup vs baseline: 1.1165x; 1.1165x over previous
//
#include <hip/hip_runtime.h>
#include <math.h>

#define NEG_SLOPE 0.2f
#define BSHIFT 8            // 256 nodes per bucket
#define MAXBUK 512          // supports N up to 131072

typedef __attribute__((ext_vector_type(8))) short short8;   // 8 bf16 (MFMA A/B frag)
typedef __attribute__((ext_vector_type(4))) float floatx4;  // MFMA C/D frag

static __device__ __forceinline__ float lrelu_exp(float e) {
    e = fmaxf(e, NEG_SLOPE * e);
    return __expf(e);
}

// fp32 -> bf16 (round-to-nearest-even)
static __device__ __forceinline__ short f2bf(float f) {
    union { float f; unsigned u; } v; v.f = f;
    unsigned r = v.u + 0x7FFFu + ((v.u >> 16) & 1u);
    return (short)(r >> 16);
}
// bf16 bits -> fp32 (exact)
static __device__ __forceinline__ float bf2f(unsigned short s) {
    union { float f; unsigned u; } v;
    v.u = ((unsigned)s) << 16;
    return v.f;
}
// packed pair of bf16 -> two fp32 (1 shift / 1 and)
static __device__ __forceinline__ float bfpair_lo(unsigned v) {
    union { float f; unsigned u; } x; x.u = v << 16; return x.f;
}
static __device__ __forceinline__ float bfpair_hi(unsigned v) {
    union { float f; unsigned u; } x; x.u = v & 0xffff0000u; return x.f;
}
// split f into hi+lo bf16 pair (covers ~16 mantissa bits)
static __device__ __forceinline__ void splitbf(float f, short& hi, short& lo) {
    hi = f2bf(f);
    lo = f2bf(f - bf2f((unsigned short)hi));
}

// ================= CSR build: LDS-bucketed partition (no global data atomics) =================

__global__ __launch_bounds__(512) void k_hist(const int* __restrict__ dst, int E, int CHUNK,
                                              int NBLK, int NBUK, int* __restrict__ blockhist) {
    __shared__ int hist[MAXBUK];
    int t = threadIdx.x, b = blockIdx.x;
    for (int i = t; i < NBUK; i += 512) hist[i] = 0;
    __syncthreads();
    int e0 = b * CHUNK, e1 = e0 + CHUNK; if (e1 > E) e1 = E;
    for (int e = e0 + t; e < e1; e += 512) atomicAdd(&hist[dst[e] >> BSHIFT], 1);
    __syncthreads();
    for (int i = t; i < NBUK; i += 512) blockhist[(size_t)i * NBLK + b] = hist[i];
}

// Per-bucket LOCAL exclusive scan across NBLK block-counts (carry loop), writes bucket total.
__global__ __launch_bounds__(256) void k_colscan(int* __restrict__ blockhist,
                                                 int* __restrict__ btot, int NBLK) {
    int bucket = blockIdx.x, t = threadIdx.x;
    int lane = t & 63, wv = t >> 6;
    __shared__ int wsum[4];
    __shared__ int carry_s;
    if (t == 0) carry_s = 0;
    __syncthreads();
    for (int base = 0; base < NBLK; base += 256) {
        int idx = base + t;
        int v = (idx < NBLK) ? blockhist[(size_t)bucket * NBLK + idx] : 0;
        int s = v;
#pragma unroll
        for (int o = 1; o < 64; o <<= 1) {
            int u = __shfl_up(s, o, 64);
            if (lane >= o) s += u;
        }
        if (lane == 63) wsum[wv] = s;
        __syncthreads();
        int b0 = 0;
#pragma unroll
        for (int w = 0; w < 4; ++w) b0 += (w < wv) ? wsum[w] : 0;
        int excl = s + b0 - v + carry_s;
        if (idx < NBLK) blockhist[(size_t)bucket * NBLK + idx] = excl;
        __syncthreads();
        if (t == 255) carry_s += s + b0;   // chunk total
        __syncthreads();
    }
    if (t == 0) btot[bucket] = carry_s;
}

// Exclusive scan over NBUK bucket totals (NBUK <= 512).
__global__ __launch_bounds__(512) void k_bucket_scan(const int* __restrict__ btot,
                                                     int* __restrict__ bucketbase, int NBUK) {
    __shared__ int sh[512];
    int t = threadIdx.x;
    int v = (t < NBUK) ? btot[t] : 0;
    sh[t] = v;
    __syncthreads();
#pragma unroll
    for (int o = 1; o < 512; o <<= 1) {
        int u = (t >= o) ? sh[t - o] : 0;
        __syncthreads();
        sh[t] += u;
        __syncthreads();
    }
    if (t < NBUK) bucketbase[t] = sh[t] - v;
    if (t == NBUK - 1) bucketbase[NBUK] = sh[t];
}

// packed record: (src << 8) | (dst & 255)   [src < 2^24; bucket id recovers dst high bits]
__global__ __launch_bounds__(512) void k_partition(const int* __restrict__ src,
                                                   const int* __restrict__ dst, int E, int CHUNK,
                                                   int NBLK, int NBUK,
                                                   const int* __restrict__ blockhist,
                                                   const int* __restrict__ bucketbase,
                                                   unsigned* __restrict__ packed) {
    __shared__ int cur[MAXBUK];
    int t = threadIdx.x, b = blockIdx.x;
    for (int i = t; i < NBUK; i += 512)
        cur[i] = blockhist[(size_t)i * NBLK + b] + bucketbase[i];
    __syncthreads();
    int e0 = b * CHUNK, e1 = e0 + CHUNK; if (e1 > E) e1 = E;
    for (int e = e0 + t; e < e1; e += 512) {
        int d = dst[e], s = src[e];
        int pos = atomicAdd(&cur[d >> BSHIFT], 1);
        packed[pos] = ((unsigned)s << 8) | ((unsigned)d & 255u);
    }
}

__global__ __launch_bounds__(256) void k_fine(const unsigned* __restrict__ packed,
                                              const int* __restrict__ bucketbase,
                                              int* __restrict__ offsets,
                                              int* __restrict__ csr_src,
                                              int N, int NBUK) {
    __shared__ int fcnt[256];
    __shared__ int wsum[4];
    int bucket = blockIdx.x, t = threadIdx.x;
    int lo = bucket << BSHIFT;
    int nn = N - lo; if (nn > 256) nn = 256;
    int ebase = bucketbase[bucket];
    int ecnt = bucketbase[bucket + 1] - ebase;
    fcnt[t] = 0;
    __syncthreads();
    for (int i = t; i < ecnt; i += 256) {
        unsigned p = packed[ebase + i];
        atomicAdd(&fcnt[p & 255u], 1);
    }
    __syncthreads();
    int v = fcnt[t];
    int lane = t & 63, wv = t >> 6;
    int s = v;
#pragma unroll
    for (int o = 1; o < 64; o <<= 1) {
        int u = __shfl_up(s, o, 64);
        if (lane >= o) s += u;
    }
    if (lane == 63) wsum[wv] = s;
    __syncthreads();
    int base = 0;
#pragma unroll
    for (int w = 0; w < 4; ++w) base += (w < wv) ? wsum[w] : 0;
    int excl = s + base - v;
    if (t < nn) offsets[lo + t] = ebase + excl;
    if (bucket == NBUK - 1 && t == 0) offsets[N] = ebase + ecnt;  // == E
    __syncthreads();
    fcnt[t] = excl;   // reuse as cursor
    __syncthreads();
    for (int i = t; i < ecnt; i += 256) {
        unsigned p = packed[ebase + i];
        int pos = atomicAdd(&fcnt[p & 255u], 1);
        csr_src[ebase + pos] = (int)(p >> 8);
    }
}

// ---------------- W2 pre-split: hi/lo bf16, padded 40 -> 48 cols ----------------
__global__ __launch_bounds__(256) void k_splitW2(const float* __restrict__ W2,
                                                 short* __restrict__ w2h,
                                                 short* __restrict__ w2l) {
    int i = blockIdx.x * 256 + threadIdx.x;
    if (i < 64 * 48) {
        int row = i / 48, col = i % 48;
        short hi = 0, lo = 0;
        if (col < 40) splitbf(W2[row * 40 + col], hi, lo);
        w2h[i] = hi; w2l[i] = lo;
    }
}

// ---------------- Layer 1 GEMM via MFMA bf16 (plain; inputs replay-constant) ----------------
__global__ __launch_bounds__(256) void k_gemm1(const float* __restrict__ x,
                                               const float* __restrict__ W1,
                                               const float* __restrict__ att_s,
                                               const float* __restrict__ att_d,
                                               unsigned short* __restrict__ h1b,
                                               float* __restrict__ a_s1,
                                               float* __restrict__ a_d1, int N) {
    int tid = threadIdx.x, wave = tid >> 6, lane = tid & 63;
    int n16 = lane & 15, q = lane >> 4;
    int nb = blockIdx.x * 64 + wave * 16;
    if (nb >= N) return;

    short8 bfr[4][4];
#pragma unroll
    for (int ct = 0; ct < 4; ++ct) {
        int n = ct * 16 + n16;
#pragma unroll
        for (int kc = 0; kc < 4; ++kc) {
            int k0 = kc * 32 + q * 8;
            short8 b;
#pragma unroll
            for (int j = 0; j < 8; ++j) b[j] = f2bf(W1[(k0 + j) * 64 + n]);
            bfr[ct][kc] = b;
        }
    }

    int arow = nb + n16; if (arow >= N) arow = N - 1;
    const float* xr = x + (size_t)arow * 128 + q * 8;
    short8 afr[4];
#pragma unroll
    for (int kc = 0; kc < 4; ++kc) {
        float4 u0 = *(const float4*)(xr + kc * 32);
        float4 u1 = *(const float4*)(xr + kc * 32 + 4);
        short8 a;
        a[0] = f2bf(u0.x); a[1] = f2bf(u0.y); a[2] = f2bf(u0.z); a[3] = f2bf(u0.w);
        a[4] = f2bf(u1.x); a[5] = f2bf(u1.y); a[6] = f2bf(u1.z); a[7] = f2bf(u1.w);
        afr[kc] = a;
    }

    floatx4 acc[4];
#pragma unroll
    for (int ct = 0; ct < 4; ++ct) {
        floatx4 c = {0.f, 0.f, 0.f, 0.f};
#pragma unroll
        for (int kc = 0; kc < 4; ++kc)
            c = __builtin_amdgcn_mfma_f32_16x16x32_bf16(afr[kc], bfr[ct][kc], c, 0, 0, 0);
        acc[ct] = c;
    }

#pragma unroll
    for (int ct = 0; ct < 4; ++ct) {
#pragma unroll
        for (int r = 0; r < 4; ++r) {
            int row = nb + q * 4 + r;
            if (row < N) h1b[(size_t)row * 64 + ct * 16 + n16] = (unsigned short)f2bf(acc[ct][r]);
        }
    }

#pragma unroll
    for (int ct = 0; ct < 4; ++ct) {
        float as = att_s[ct * 16 + n16];
        float ad = att_d[ct * 16 + n16];
#pragma unroll
        for (int r = 0; r < 4; ++r) {
            float ps = acc[ct][r] * as;
            float pd = acc[ct][r] * ad;
#pragma unroll
            for (int m = 1; m < 8; m <<= 1) {
                ps += __shfl_xor(ps, m, 64);
                pd += __shfl_xor(pd, m, 64);
            }
            int row = nb + q * 4 + r;
            if ((n16 & 7) == 0 && row < N) {
                int h = 2 * ct + (n16 >> 3);
                a_s1[row * 8 + h] = ps;
                a_d1[row * 8 + h] = pd;
            }
        }
    }
}

// ---------------- Layer 1 aggregation: R12 head-per-lane scheme (proven) ----------------------
// lane = (g, h): g = lane>>3 edge slot (8 edges per step), h = lane&7 head.
__global__ __launch_bounds__(256) void k_agg1(const unsigned short* __restrict__ h1b,
                                              const float* __restrict__ a_s1,
                                              const float* __restrict__ a_d1,
                                              const int* __restrict__ offsets,
                                              const int* __restrict__ csr_src,
                                              const float* __restrict__ b1,
                                              float* __restrict__ y1, int N) {
    int wave = threadIdx.x >> 6, lane = threadIdx.x & 63;
    int d = blockIdx.x * 4 + wave;
    if (d >= N) return;
    int g = lane >> 3;           // edge slot within an 8-edge step
    int h = lane & 7;            // head (channels 8h..8h+7)
    float ad = a_d1[d * 8 + h];
    float acc[8] = {0.f, 0.f, 0.f, 0.f, 0.f, 0.f, 0.f, 0.f};
    float wsum_l = 0.f;
    if (g == 0) {                // self-loop on slot 0
        float w0 = lrelu_exp(a_s1[d * 8 + h] + ad);
        uint4 v = *(const uint4*)(h1b + (size_t)d * 64 + 8 * h);
        acc[0] = w0 * bfpair_lo(v.x); acc[1] = w0 * bfpair_hi(v.x);
        acc[2] = w0 * bfpair_lo(v.y); acc[3] = w0 * bfpair_hi(v.y);
        acc[4] = w0 * bfpair_lo(v.z); acc[5] = w0 * bfpair_hi(v.z);
        acc[6] = w0 * bfpair_lo(v.w); acc[7] = w0 * bfpair_hi(v.w);
        wsum_l = w0;
    }
    int i0 = offsets[d], i1 = offsets[d + 1];
    for (int base = i0; base < i1; base += 64) {
        int m = i1 - base; if (m > 64) m = 64;
        int sv = (lane < m) ? csr_src[base + lane] : 0;
        for (int j = 0; j < m; j += 16) {
            int eA = j + g;
            int siA = __shfl(sv, eA, 64);
            bool liveB = (j + 8 < m);
            if (liveB) {
                int eB = j + 8 + g;
                int siB = __shfl(sv, eB, 64);
                float evA = a_s1[siA * 8 + h] + ad;
                float evB = a_s1[siB * 8 + h] + ad;
                uint4 vA = *(const uint4*)(h1b + (size_t)siA * 64 + 8 * h);
                uint4 vB = *(const uint4*)(h1b + (size_t)siB * 64 + 8 * h);
                float wA = (eA < m) ? lrelu_exp(evA) : 0.f;
                float wB = (eB < m) ? lrelu_exp(evB) : 0.f;
                wsum_l += wA + wB;
                acc[0] = fmaf(wA, bfpair_lo(vA.x), acc[0]);
                acc[1] = fmaf(wA, bfpair_hi(vA.x), acc[1]);
                acc[2] = fmaf(wA, bfpair_lo(vA.y), acc[2]);
                acc[3] = fmaf(wA, bfpair_hi(vA.y), acc[3]);
                acc[4] = fmaf(wA, bfpair_lo(vA.z), acc[4]);
                acc[5] = fmaf(wA, bfpair_hi(vA.z), acc[5]);
                acc[6] = fmaf(wA, bfpair_lo(vA.w), acc[6]);
                acc[7] = fmaf(wA, bfpair_hi(vA.w), acc[7]);
                acc[0] = fmaf(wB, bfpair_lo(vB.x), acc[0]);
                acc[1] = fmaf(wB, bfpair_hi(vB.x), acc[1]);
                acc[2] = fmaf(wB, bfpair_lo(vB.y), acc[2]);
                acc[3] = fmaf(wB, bfpair_hi(vB.y), acc[3]);
                acc[4] = fmaf(wB, bfpair_lo(vB.z), acc[4]);
                acc[5] = fmaf(wB, bfpair_hi(vB.z), acc[5]);
                acc[6] = fmaf(wB, bfpair_lo(vB.w), acc[6]);
                acc[7] = fmaf(wB, bfpair_hi(vB.w), acc[7]);
            } else {
                float evA = a_s1[siA * 8 + h] + ad;
                uint4 vA = *(const uint4*)(h1b + (size_t)siA * 64 + 8 * h);
                float wA = (eA < m) ? lrelu_exp(evA) : 0.f;
                wsum_l += wA;
                acc[0] = fmaf(wA, bfpair_lo(vA.x), acc[0]);
                acc[1] = fmaf(wA, bfpair_hi(vA.x), acc[1]);
                acc[2] = fmaf(wA, bfpair_lo(vA.y), acc[2]);
                acc[3] = fmaf(wA, bfpair_hi(vA.y), acc[3]);
                acc[4] = fmaf(wA, bfpair_lo(vA.z), acc[4]);
                acc[5] = fmaf(wA, bfpair_hi(vA.z), acc[5]);
                acc[6] = fmaf(wA, bfpair_lo(vA.w), acc[6]);
                acc[7] = fmaf(wA, bfpair_hi(vA.w), acc[7]);
            }
        }
    }
    // reduce across the 8 edge slots (lanes h, h+8, ..., h+56)
#pragma unroll
    for (int mm = 8; mm < 64; mm <<= 1) {
#pragma unroll
        for (int k = 0; k < 8; ++k) acc[k] += __shfl_xor(acc[k], mm, 64);
        wsum_l += __shfl_xor(wsum_l, mm, 64);
    }
    if (g == 0) {
        float inv = 1.f / (wsum_l + 1e-16f);
        float4 bA = *(const float4*)(b1 + 8 * h);
        float4 bB = *(const float4*)(b1 + 8 * h + 4);
        float o[8];
        o[0] = acc[0] * inv + bA.x;
        o[1] = acc[1] * inv + bA.y;
        o[2] = acc[2] * inv + bA.z;
        o[3] = acc[3] * inv + bA.w;
        o[4] = acc[4] * inv + bB.x;
        o[5] = acc[5] * inv + bB.y;
        o[6] = acc[6] * inv + bB.z;
        o[7] = acc[7] * inv + bB.w;
#pragma unroll
        for (int k = 0; k < 8; ++k) o[k] = o[k] > 0.f ? o[k] : (__expf(o[k]) - 1.f);
        float4 s0 = make_float4(o[0], o[1], o[2], o[3]);
        float4 s1 = make_float4(o[4], o[5], o[6], o[7]);
        *(float4*)(y1 + (size_t)d * 64 + 8 * h) = s0;       // fp32 (precision-critical)
        *(float4*)(y1 + (size_t)d * 64 + 8 * h + 4) = s1;
    }
}

// ---------------- Layer 2 GEMM, split-bf16 (y1 replay-variant -> fp32-class needed) ----------
__global__ __launch_bounds__(256) void k_gemm2(const float* __restrict__ y1,
                                               const short* __restrict__ w2h,
                                               const short* __restrict__ w2l,
                                               const float* __restrict__ att_s,
                                               const float* __restrict__ att_d,
                                               unsigned short* __restrict__ h2b,
                                               float* __restrict__ a2s,
                                               float* __restrict__ a2d, int N) {
    int tid = threadIdx.x, wave = tid >> 6, lane = tid & 63;
    int n16 = lane & 15, q = lane >> 4;
    int nb = blockIdx.x * 64 + wave * 16;
    if (nb >= N) return;

    int arow = nb + n16; if (arow >= N) arow = N - 1;
    const float* yr = y1 + (size_t)arow * 64 + q * 8;
    short8 ah[2], al[2];
#pragma unroll
    for (int kc = 0; kc < 2; ++kc) {
        float4 u0 = *(const float4*)(yr + kc * 32);
        float4 u1 = *(const float4*)(yr + kc * 32 + 4);
        short8 h, l; short hi, lo;
        splitbf(u0.x, hi, lo); h[0] = hi; l[0] = lo;
        splitbf(u0.y, hi, lo); h[1] = hi; l[1] = lo;
        splitbf(u0.z, hi, lo); h[2] = hi; l[2] = lo;
        splitbf(u0.w, hi, lo); h[3] = hi; l[3] = lo;
        splitbf(u1.x, hi, lo); h[4] = hi; l[4] = lo;
        splitbf(u1.y, hi, lo); h[5] = hi; l[5] = lo;
        splitbf(u1.z, hi, lo); h[6] = hi; l[6] = lo;
        splitbf(u1.w, hi, lo); h[7] = hi; l[7] = lo;
        ah[kc] = h; al[kc] = l;
    }

    float psr[4] = {0.f, 0.f, 0.f, 0.f}, pdr[4] = {0.f, 0.f, 0.f, 0.f};
#pragma unroll
    for (int ct = 0; ct < 3; ++ct) {
        int n = ct * 16 + n16;
        short8 bh0, bh1, bl0, bl1;
#pragma unroll
        for (int j = 0; j < 8; ++j) {
            int k0 = q * 8 + j;
            bh0[j] = w2h[k0 * 48 + n];
            bl0[j] = w2l[k0 * 48 + n];
            bh1[j] = w2h[(32 + k0) * 48 + n];
            bl1[j] = w2l[(32 + k0) * 48 + n];
        }
        floatx4 c = {0.f, 0.f, 0.f, 0.f};
        c = __builtin_amdgcn_mfma_f32_16x16x32_bf16(ah[0], bl0, c, 0, 0, 0);
        c = __builtin_amdgcn_mfma_f32_16x16x32_bf16(al[0], bh0, c, 0, 0, 0);
        c = __builtin_amdgcn_mfma_f32_16x16x32_bf16(ah[0], bh0, c, 0, 0, 0);
        c = __builtin_amdgcn_mfma_f32_16x16x32_bf16(ah[1], bl1, c, 0, 0, 0);
        c = __builtin_amdgcn_mfma_f32_16x16x32_bf16(al[1], bh1, c, 0, 0, 0);
        c = __builtin_amdgcn_mfma_f32_16x16x32_bf16(ah[1], bh1, c, 0, 0, 0);

        int col = ct * 16 + n16;
#pragma unroll
        for (int r = 0; r < 4; ++r) {
            int row = nb + q * 4 + r;
            if (col < 40 && row < N) h2b[(size_t)row * 40 + col] = (unsigned short)f2bf(c[r]);
        }
        float asv = (col < 40) ? att_s[col] : 0.f;
        float adv = (col < 40) ? att_d[col] : 0.f;
#pragma unroll
        for (int r = 0; r < 4; ++r) {
            psr[r] = fmaf(c[r], asv, psr[r]);
            pdr[r] = fmaf(c[r], adv, pdr[r]);
        }
    }
#pragma unroll
    for (int r = 0; r < 4; ++r) {
        float ps = psr[r], pd = pdr[r];
#pragma unroll
        for (int m = 1; m < 16; m <<= 1) {
            ps += __shfl_xor(ps, m, 64);
            pd += __shfl_xor(pd, m, 64);
        }
        int row = nb + q * 4 + r;
        if (n16 == 0 && row < N) { a2s[row] = ps; a2d[row] = pd; }
    }
}

// ---------------- Layer 2 aggregation: R14 node-per-quarter, shfl-free main loop ------------
// 4 nodes/wave. Quarter q (lanes 16q..16q+15): ll = g*5+c for ll<15 (g=0..2 edge slot,
// c=0..4 16B row chunk), lane 15 idle. Each lane DIRECTLY loads csr_src[i0+j+g] (5-way
// same-address broadcast) and redundantly computes the exp -- redundant per-lane work is
// free wave-instruction-wise. Zero shfls in main loop; epilogue amortized over 4 nodes.
__global__ __launch_bounds__(256) void k_agg2(const unsigned short* __restrict__ h2b,
                                              const float* __restrict__ a2s,
                                              const float* __restrict__ a2d,
                                              const int* __restrict__ offsets,
                                              const int* __restrict__ csr_src,
                                              const float* __restrict__ b2,
                                              float* __restrict__ out, int N) {
    int wave = threadIdx.x >> 6, lane = threadIdx.x & 63;
    int q = lane >> 4;                   // quarter = node slot
    int ll = lane & 15;                  // lane within quarter
    int d = (blockIdx.x * 4 + wave) * 4 + q;
    bool dvalid = (d < N);
    int de = dvalid ? d : N - 1;
    int g = ll / 5;                      // edge slot 0..2 (3 for idle lane 15)
    int c = ll - g * 5;                  // 16B chunk 0..4
    bool lane_ok = (ll < 15);
    float ad = a2d[de];
    float w0 = lrelu_exp(a2s[de] + ad);
    int i0 = offsets[de];
    int deg = offsets[de + 1] - i0;
    if (!dvalid) deg = 0;
    // max degree across the 4 quarters -> uniform loop bound
    int dmax = deg;
    dmax = max(dmax, __shfl_xor(dmax, 16, 64));
    dmax = max(dmax, __shfl_xor(dmax, 32, 64));
    float acc[8] = {0.f, 0.f, 0.f, 0.f, 0.f, 0.f, 0.f, 0.f};
    float wsum_l = 0.f;
    if (g == 0) {                        // self-loop handled by g==0 lanes (ll 0..4)
        uint4 v = *(const uint4*)(h2b + (size_t)de * 40 + 8 * c);
        acc[0] = w0 * bfpair_lo(v.x); acc[1] = w0 * bfpair_hi(v.x);
        acc[2] = w0 * bfpair_lo(v.y); acc[3] = w0 * bfpair_hi(v.y);
        acc[4] = w0 * bfpair_lo(v.z); acc[5] = w0 * bfpair_hi(v.z);
        acc[6] = w0 * bfpair_lo(v.w); acc[7] = w0 * bfpair_hi(v.w);
    }
    for (int j = 0; j < dmax; j += 6) {
        int jA = j + g, jB = j + 3 + g;
        bool liveA = lane_ok && (jA < deg);
        bool liveB = lane_ok && (jB < deg);
        int svA = de, svB = de;
        if (liveA) svA = csr_src[i0 + jA];
        if (liveB) svB = csr_src[i0 + jB];
        float eA = a2s[svA] + ad;
        float eB = a2s[svB] + ad;
        uint4 vA = *(const uint4*)(h2b + (size_t)svA * 40 + 8 * c);
        uint4 vB = *(const uint4*)(h2b + (size_t)svB * 40 + 8 * c);
        float wA = liveA ? lrelu_exp(eA) : 0.f;
        float wB = liveB ? lrelu_exp(eB) : 0.f;
        if (c == 0) wsum_l += wA + wB;   // one counting lane per (quarter, slot)
        acc[0] = fmaf(wA, bfpair_lo(vA.x), acc[0]);
        acc[1] = fmaf(wA, bfpair_hi(vA.x), acc[1]);
        acc[2] = fmaf(wA, bfpair_lo(vA.y), acc[2]);
        acc[3] = fmaf(wA, bfpair_hi(vA.y), acc[3]);
        acc[4] = fmaf(wA, bfpair_lo(vA.z), acc[4]);
        acc[5] = fmaf(wA, bfpair_hi(vA.z), acc[5]);
        acc[6] = fmaf(wA, bfpair_lo(vA.w), acc[6]);
        acc[7] = fmaf(wA, bfpair_hi(vA.w), acc[7]);
        acc[0] = fmaf(wB, bfpair_lo(vB.x), acc[0]);
        acc[1] = fmaf(wB, bfpair_hi(vB.x), acc[1]);
        acc[2] = fmaf(wB, bfpair_lo(vB.y), acc[2]);
        acc[3] = fmaf(wB, bfpair_hi(vB.y), acc[3]);
        acc[4] = fmaf(wB, bfpair_lo(vB.z), acc[4]);
        acc[5] = fmaf(wB, bfpair_hi(vB.z), acc[5]);
        acc[6] = fmaf(wB, bfpair_lo(vB.w), acc[6]);
        acc[7] = fmaf(wB, bfpair_hi(vB.w), acc[7]);
    }
    // fold 3 edge slots into g==0 lanes (same c): +5, +10 within quarter
#pragma unroll
    for (int k = 0; k < 8; ++k)
        acc[k] += __shfl(acc[k], lane + 5, 64) + __shfl(acc[k], lane + 10, 64);
    wsum_l += __shfl(wsum_l, lane + 5, 64) + __shfl(wsum_l, lane + 10, 64);
    wsum_l = __shfl(wsum_l, lane & 48, 64);       // broadcast quarter total (from ll==0)
    float wsum = wsum_l + w0;
    bool act5 = (ll < 5) && dvalid;
    float inv = 1.f / (wsum + 1e-16f);
    float4 bA = *(const float4*)(b2 + 8 * c);
    float4 bB = *(const float4*)(b2 + 8 * c + 4);
    float o[8];
    o[0] = acc[0] * inv + bA.x;
    o[1] = acc[1] * inv + bA.y;
    o[2] = acc[2] * inv + bA.z;
    o[3] = acc[3] * inv + bA.w;
    o[4] = acc[4] * inv + bB.x;
    o[5] = acc[5] * inv + bB.y;
    o[6] = acc[6] * inv + bB.z;
    o[7] = acc[7] * inv + bB.w;
    // log_softmax over 40 ch: ll 0..4 hold 8 each; 3-step butterfly inside 8-lane group
    float mxl = -INFINITY;
    if (act5) {
        mxl = fmaxf(fmaxf(fmaxf(o[0], o[1]), fmaxf(o[2], o[3])),
                    fmaxf(fmaxf(o[4], o[5]), fmaxf(o[6], o[7])));
    }
#pragma unroll
    for (int mm = 1; mm < 8; mm <<= 1) mxl = fmaxf(mxl, __shfl_xor(mxl, mm, 64));
    float exl = 0.f;
    if (act5) {
#pragma unroll
        for (int k = 0; k < 8; ++k) exl += __expf(o[k] - mxl);
    }
#pragma unroll
    for (int mm = 1; mm < 8; mm <<= 1) exl += __shfl_xor(exl, mm, 64);
    if (act5) {
        float lse = mxl + __logf(exl);
        float4 s0 = make_float4(o[0] - lse, o[1] - lse, o[2] - lse, o[3] - lse);
        float4 s1 = make_float4(o[4] - lse, o[5] - lse, o[6] - lse, o[7] - lse);
        *(float4*)(out + (size_t)d * 40 + 8 * c) = s0;
        *(float4*)(out + (size_t)d * 40 + 8 * c + 4) = s1;
    }
}

// ---------------- launcher ----------------

extern "C" void kernel_launch(void* const* d_in, const int* in_sizes, int n_in,
                              void* d_out, int out_size, void* d_ws, size_t ws_size,
                              hipStream_t stream) {
    const float* x   = (const float*)d_in[0];
    const int*   ei  = (const int*)d_in[1];
    const float* W1  = (const float*)d_in[2];
    const float* as1 = (const float*)d_in[3];
    const float* ad1 = (const float*)d_in[4];
    const float* b1  = (const float*)d_in[5];
    const float* W2  = (const float*)d_in[6];
    const float* as2 = (const float*)d_in[7];
    const float* ad2 = (const float*)d_in[8];
    const float* b2  = (const float*)d_in[9];
    float* out = (float*)d_out;

    int N = in_sizes[0] / 128;   // 100000
    int E = in_sizes[1] / 2;     // 1600000
    const int* src = ei;
    const int* dst = ei + E;

    int NBUK = (N + 255) >> BSHIFT;          // 391
    int CHUNK = 4096;
    int NBLK = (E + CHUNK - 1) / CHUNK;      // 391

    char* ws = (char*)d_ws;
    size_t off = 0;
    auto alloc = [&](size_t bytes) -> char* {
        char* p = ws + off;
        off += (bytes + 255) & ~(size_t)255;
        return p;
    };
    unsigned short* h1b = (unsigned short*)alloc((size_t)N * 64 * 2);   // bf16
    float* a_s1    = (float*)alloc((size_t)N * 8 * 4);
    float* a_d1    = (float*)alloc((size_t)N * 8 * 4);
    float* y1      = (float*)alloc((size_t)N * 64 * 4);                 // fp32 (precision-critical)
    // h2b (bf16, 8 MB) and packed (uint, 6.4 MB) are temporally disjoint: share region.
    size_t shared_sz = (size_t)N * 40 * 2;
    if ((size_t)E * 4 > shared_sz) shared_sz = (size_t)E * 4;
    char*  region  = alloc(shared_sz);
    unsigned short* h2b = (unsigned short*)region;
    unsigned* packed    = (unsigned*)region;
    float* a2s     = (float*)alloc((size_t)N * 4);
    float* a2d     = (float*)alloc((size_t)N * 4);
    int*   offsets = (int*)alloc((size_t)(N + 1) * 4);
    int*   csr_src = (int*)alloc((size_t)E * 4);
    int*   blockhist  = (int*)alloc((size_t)NBUK * NBLK * 4);
    int*   btot       = (int*)alloc((size_t)NBUK * 4);
    int*   bucketbase = (int*)alloc((size_t)(NBUK + 1) * 4);
    short* w2h     = (short*)alloc((size_t)64 * 48 * 2);
    short* w2l     = (short*)alloc((size_t)64 * 48 * 2);

    int nb = (N + 3) / 4;
    int nb2 = (N + 15) / 16;     // agg2: 16 nodes per block (4 waves x 4 quarters)
    int gb = (N + 63) / 64;

    k_hist<<<NBLK, 512, 0, stream>>>(dst, E, CHUNK, NBLK, NBUK, blockhist);
    k_colscan<<<NBUK, 256, 0, stream>>>(blockhist, btot, NBLK);
    k_bucket_scan<<<1, 512, 0, stream>>>(btot, bucketbase, NBUK);
    k_partition<<<NBLK, 512, 0, stream>>>(src, dst, E, CHUNK, NBLK, NBUK, blockhist,
                                          bucketbase, packed);
    k_fine<<<NBUK, 256, 0, stream>>>(packed, bucketbase, offsets, csr_src, N, NBUK);
    k_splitW2<<<12, 256, 0, stream>>>(W2, w2h, w2l);
    k_gemm1<<<gb, 256, 0, stream>>>(x, W1, as1, ad1, h1b, a_s1, a_d1, N);
    k_agg1<<<nb, 256, 0, stream>>>(h1b, a_s1, a_d1, offsets, csr_src, b1, y1, N);
    k_gemm2<<<gb, 256, 0, stream>>>(y1, w2h, w2l, as2, ad2, h2b, a2s, a2d, N);
    k_agg2<<<nb2, 256, 0, stream>>>(h2b, a2s, a2d, offsets, csr_src, b2, out, N);
}

// Round 4
// 171.158 us; speedup vs baseline: 1.1261x; 1.0086x over previous
//
#include <hip/hip_runtime.h>
#include <math.h>

#define NEG_SLOPE 0.2f
#define BSHIFT 8            // 256 nodes per bucket
#define MAXBUK 512          // supports N up to 131072

typedef __attribute__((ext_vector_type(8))) short short8;   // 8 bf16 (MFMA A/B frag)
typedef __attribute__((ext_vector_type(4))) float floatx4;  // MFMA C/D frag

static __device__ __forceinline__ float lrelu_exp(float e) {
    e = fmaxf(e, NEG_SLOPE * e);
    return __expf(e);
}

// fp32 -> bf16 (round-to-nearest-even)
static __device__ __forceinline__ short f2bf(float f) {
    union { float f; unsigned u; } v; v.f = f;
    unsigned r = v.u + 0x7FFFu + ((v.u >> 16) & 1u);
    return (short)(r >> 16);
}
// bf16 bits -> fp32 (exact)
static __device__ __forceinline__ float bf2f(unsigned short s) {
    union { float f; unsigned u; } v;
    v.u = ((unsigned)s) << 16;
    return v.f;
}
// packed pair of bf16 -> two fp32 (1 shift / 1 and)
static __device__ __forceinline__ float bfpair_lo(unsigned v) {
    union { float f; unsigned u; } x; x.u = v << 16; return x.f;
}
static __device__ __forceinline__ float bfpair_hi(unsigned v) {
    union { float f; unsigned u; } x; x.u = v & 0xffff0000u; return x.f;
}
// split f into hi+lo bf16 pair (covers ~16 mantissa bits)
static __device__ __forceinline__ void splitbf(float f, short& hi, short& lo) {
    hi = f2bf(f);
    lo = f2bf(f - bf2f((unsigned short)hi));
}

// ================= CSR build: LDS-bucketed partition (no global data atomics) =================

__global__ __launch_bounds__(512) void k_hist(const int* __restrict__ dst, int E, int CHUNK,
                                              int NBLK, int NBUK, int* __restrict__ blockhist) {
    __shared__ int hist[MAXBUK];
    int t = threadIdx.x, b = blockIdx.x;
    for (int i = t; i < NBUK; i += 512) hist[i] = 0;
    __syncthreads();
    int e0 = b * CHUNK, e1 = e0 + CHUNK; if (e1 > E) e1 = E;
    for (int e = e0 + t; e < e1; e += 512) atomicAdd(&hist[dst[e] >> BSHIFT], 1);
    __syncthreads();
    for (int i = t; i < NBUK; i += 512) blockhist[(size_t)i * NBLK + b] = hist[i];
}

// Per-bucket LOCAL exclusive scan across NBLK block-counts (carry loop), writes bucket total.
__global__ __launch_bounds__(256) void k_colscan(int* __restrict__ blockhist,
                                                 int* __restrict__ btot, int NBLK) {
    int bucket = blockIdx.x, t = threadIdx.x;
    int lane = t & 63, wv = t >> 6;
    __shared__ int wsum[4];
    __shared__ int carry_s;
    if (t == 0) carry_s = 0;
    __syncthreads();
    for (int base = 0; base < NBLK; base += 256) {
        int idx = base + t;
        int v = (idx < NBLK) ? blockhist[(size_t)bucket * NBLK + idx] : 0;
        int s = v;
#pragma unroll
        for (int o = 1; o < 64; o <<= 1) {
            int u = __shfl_up(s, o, 64);
            if (lane >= o) s += u;
        }
        if (lane == 63) wsum[wv] = s;
        __syncthreads();
        int b0 = 0;
#pragma unroll
        for (int w = 0; w < 4; ++w) b0 += (w < wv) ? wsum[w] : 0;
        int excl = s + b0 - v + carry_s;
        if (idx < NBLK) blockhist[(size_t)bucket * NBLK + idx] = excl;
        __syncthreads();
        if (t == 255) carry_s += s + b0;   // chunk total
        __syncthreads();
    }
    if (t == 0) btot[bucket] = carry_s;
}

// Exclusive scan over NBUK bucket totals (NBUK <= 512).
__global__ __launch_bounds__(512) void k_bucket_scan(const int* __restrict__ btot,
                                                     int* __restrict__ bucketbase, int NBUK) {
    __shared__ int sh[512];
    int t = threadIdx.x;
    int v = (t < NBUK) ? btot[t] : 0;
    sh[t] = v;
    __syncthreads();
#pragma unroll
    for (int o = 1; o < 512; o <<= 1) {
        int u = (t >= o) ? sh[t - o] : 0;
        __syncthreads();
        sh[t] += u;
        __syncthreads();
    }
    if (t < NBUK) bucketbase[t] = sh[t] - v;
    if (t == NBUK - 1) bucketbase[NBUK] = sh[t];
}

// packed record: (src << 8) | (dst & 255)   [src < 2^24; bucket id recovers dst high bits]
__global__ __launch_bounds__(512) void k_partition(const int* __restrict__ src,
                                                   const int* __restrict__ dst, int E, int CHUNK,
                                                   int NBLK, int NBUK,
                                                   const int* __restrict__ blockhist,
                                                   const int* __restrict__ bucketbase,
                                                   unsigned* __restrict__ packed) {
    __shared__ int cur[MAXBUK];
    int t = threadIdx.x, b = blockIdx.x;
    for (int i = t; i < NBUK; i += 512)
        cur[i] = blockhist[(size_t)i * NBLK + b] + bucketbase[i];
    __syncthreads();
    int e0 = b * CHUNK, e1 = e0 + CHUNK; if (e1 > E) e1 = E;
    for (int e = e0 + t; e < e1; e += 512) {
        int d = dst[e], s = src[e];
        int pos = atomicAdd(&cur[d >> BSHIFT], 1);
        packed[pos] = ((unsigned)s << 8) | ((unsigned)d & 255u);
    }
}

__global__ __launch_bounds__(256) void k_fine(const unsigned* __restrict__ packed,
                                              const int* __restrict__ bucketbase,
                                              int* __restrict__ offsets,
                                              int* __restrict__ csr_src,
                                              int N, int NBUK) {
    __shared__ int fcnt[256];
    __shared__ int wsum[4];
    int bucket = blockIdx.x, t = threadIdx.x;
    int lo = bucket << BSHIFT;
    int nn = N - lo; if (nn > 256) nn = 256;
    int ebase = bucketbase[bucket];
    int ecnt = bucketbase[bucket + 1] - ebase;
    fcnt[t] = 0;
    __syncthreads();
    for (int i = t; i < ecnt; i += 256) {
        unsigned p = packed[ebase + i];
        atomicAdd(&fcnt[p & 255u], 1);
    }
    __syncthreads();
    int v = fcnt[t];
    int lane = t & 63, wv = t >> 6;
    int s = v;
#pragma unroll
    for (int o = 1; o < 64; o <<= 1) {
        int u = __shfl_up(s, o, 64);
        if (lane >= o) s += u;
    }
    if (lane == 63) wsum[wv] = s;
    __syncthreads();
    int base = 0;
#pragma unroll
    for (int w = 0; w < 4; ++w) base += (w < wv) ? wsum[w] : 0;
    int excl = s + base - v;
    if (t < nn) offsets[lo + t] = ebase + excl;
    if (bucket == NBUK - 1 && t == 0) offsets[N] = ebase + ecnt;  // == E
    __syncthreads();
    fcnt[t] = excl;   // reuse as cursor
    __syncthreads();
    for (int i = t; i < ecnt; i += 256) {
        unsigned p = packed[ebase + i];
        int pos = atomicAdd(&fcnt[p & 255u], 1);
        csr_src[ebase + pos] = (int)(p >> 8);
    }
}

// ---------------- W2 pre-split: hi/lo bf16, padded 40 -> 48 cols ----------------
__global__ __launch_bounds__(256) void k_splitW2(const float* __restrict__ W2,
                                                 short* __restrict__ w2h,
                                                 short* __restrict__ w2l) {
    int i = blockIdx.x * 256 + threadIdx.x;
    if (i < 64 * 48) {
        int row = i / 48, col = i % 48;
        short hi = 0, lo = 0;
        if (col < 40) splitbf(W2[row * 40 + col], hi, lo);
        w2h[i] = hi; w2l[i] = lo;
    }
}

// ---------------- Layer 1 GEMM via MFMA bf16 (plain; inputs replay-constant) ----------------
__global__ __launch_bounds__(256) void k_gemm1(const float* __restrict__ x,
                                               const float* __restrict__ W1,
                                               const float* __restrict__ att_s,
                                               const float* __restrict__ att_d,
                                               unsigned short* __restrict__ h1b,
                                               float* __restrict__ a_s1,
                                               float* __restrict__ a_d1, int N) {
    int tid = threadIdx.x, wave = tid >> 6, lane = tid & 63;
    int n16 = lane & 15, q = lane >> 4;
    int nb = blockIdx.x * 64 + wave * 16;
    if (nb >= N) return;

    short8 bfr[4][4];
#pragma unroll
    for (int ct = 0; ct < 4; ++ct) {
        int n = ct * 16 + n16;
#pragma unroll
        for (int kc = 0; kc < 4; ++kc) {
            int k0 = kc * 32 + q * 8;
            short8 b;
#pragma unroll
            for (int j = 0; j < 8; ++j) b[j] = f2bf(W1[(k0 + j) * 64 + n]);
            bfr[ct][kc] = b;
        }
    }

    int arow = nb + n16; if (arow >= N) arow = N - 1;
    const float* xr = x + (size_t)arow * 128 + q * 8;
    short8 afr[4];
#pragma unroll
    for (int kc = 0; kc < 4; ++kc) {
        float4 u0 = *(const float4*)(xr + kc * 32);
        float4 u1 = *(const float4*)(xr + kc * 32 + 4);
        short8 a;
        a[0] = f2bf(u0.x); a[1] = f2bf(u0.y); a[2] = f2bf(u0.z); a[3] = f2bf(u0.w);
        a[4] = f2bf(u1.x); a[5] = f2bf(u1.y); a[6] = f2bf(u1.z); a[7] = f2bf(u1.w);
        afr[kc] = a;
    }

    floatx4 acc[4];
#pragma unroll
    for (int ct = 0; ct < 4; ++ct) {
        floatx4 c = {0.f, 0.f, 0.f, 0.f};
#pragma unroll
        for (int kc = 0; kc < 4; ++kc)
            c = __builtin_amdgcn_mfma_f32_16x16x32_bf16(afr[kc], bfr[ct][kc], c, 0, 0, 0);
        acc[ct] = c;
    }

#pragma unroll
    for (int ct = 0; ct < 4; ++ct) {
#pragma unroll
        for (int r = 0; r < 4; ++r) {
            int row = nb + q * 4 + r;
            if (row < N) h1b[(size_t)row * 64 + ct * 16 + n16] = (unsigned short)f2bf(acc[ct][r]);
        }
    }

#pragma unroll
    for (int ct = 0; ct < 4; ++ct) {
        float as = att_s[ct * 16 + n16];
        float ad = att_d[ct * 16 + n16];
#pragma unroll
        for (int r = 0; r < 4; ++r) {
            float ps = acc[ct][r] * as;
            float pd = acc[ct][r] * ad;
#pragma unroll
            for (int m = 1; m < 8; m <<= 1) {
                ps += __shfl_xor(ps, m, 64);
                pd += __shfl_xor(pd, m, 64);
            }
            int row = nb + q * 4 + r;
            if ((n16 & 7) == 0 && row < N) {
                int h = 2 * ct + (n16 >> 3);
                a_s1[row * 8 + h] = ps;
                a_d1[row * 8 + h] = pd;
            }
        }
    }
}

// ---------------- Layer 1 aggregation: R15 node-per-quarter (ported R14 structure) ----------
// 4 nodes/wave. Quarter q (16 lanes): g = ll>>3 edge slot (0..1), c = ll&7 = 16B chunk = HEAD
// (channels 8c..8c+7; chunk==head since 8 ch x bf16 = 16B). No idle lanes. Direct broadcast
// loads of csr_src (8 lanes same addr); per-head exp is per-lane (zero redundancy); no shfls
// in main loop; epilogue (9 shfls) amortized over 4 nodes; 4-edge tail granularity.
__global__ __launch_bounds__(256) void k_agg1(const unsigned short* __restrict__ h1b,
                                              const float* __restrict__ a_s1,
                                              const float* __restrict__ a_d1,
                                              const int* __restrict__ offsets,
                                              const int* __restrict__ csr_src,
                                              const float* __restrict__ b1,
                                              float* __restrict__ y1, int N) {
    int wave = threadIdx.x >> 6, lane = threadIdx.x & 63;
    int q = lane >> 4;                   // quarter = node slot
    int ll = lane & 15;                  // lane within quarter
    int d = (blockIdx.x * 4 + wave) * 4 + q;
    bool dvalid = (d < N);
    int de = dvalid ? d : N - 1;
    int g = ll >> 3;                     // edge slot 0..1
    int c = ll & 7;                      // chunk == head
    float ad = a_d1[de * 8 + c];
    int i0 = offsets[de];
    int deg = dvalid ? (offsets[de + 1] - i0) : 0;
    // max degree across the 4 quarters -> uniform loop bound
    int dmax = deg;
    dmax = max(dmax, __shfl_xor(dmax, 16, 64));
    dmax = max(dmax, __shfl_xor(dmax, 32, 64));
    float acc[8] = {0.f, 0.f, 0.f, 0.f, 0.f, 0.f, 0.f, 0.f};
    float wsum_l = 0.f;
    if (g == 0) {                        // self-loop on slot 0
        float w0 = lrelu_exp(a_s1[de * 8 + c] + ad);
        uint4 v = *(const uint4*)(h1b + (size_t)de * 64 + 8 * c);
        acc[0] = w0 * bfpair_lo(v.x); acc[1] = w0 * bfpair_hi(v.x);
        acc[2] = w0 * bfpair_lo(v.y); acc[3] = w0 * bfpair_hi(v.y);
        acc[4] = w0 * bfpair_lo(v.z); acc[5] = w0 * bfpair_hi(v.z);
        acc[6] = w0 * bfpair_lo(v.w); acc[7] = w0 * bfpair_hi(v.w);
        wsum_l = w0;
    }
    for (int j = 0; j < dmax; j += 4) {
        int jA = j + g, jB = j + 2 + g;
        bool liveA = (jA < deg);
        bool liveB = (jB < deg);
        int svA = de, svB = de;
        if (liveA) svA = csr_src[i0 + jA];
        if (liveB) svB = csr_src[i0 + jB];
        float eA = a_s1[svA * 8 + c] + ad;
        float eB = a_s1[svB * 8 + c] + ad;
        uint4 vA = *(const uint4*)(h1b + (size_t)svA * 64 + 8 * c);
        uint4 vB = *(const uint4*)(h1b + (size_t)svB * 64 + 8 * c);
        float wA = liveA ? lrelu_exp(eA) : 0.f;
        float wB = liveB ? lrelu_exp(eB) : 0.f;
        wsum_l += wA + wB;
        acc[0] = fmaf(wA, bfpair_lo(vA.x), acc[0]);
        acc[1] = fmaf(wA, bfpair_hi(vA.x), acc[1]);
        acc[2] = fmaf(wA, bfpair_lo(vA.y), acc[2]);
        acc[3] = fmaf(wA, bfpair_hi(vA.y), acc[3]);
        acc[4] = fmaf(wA, bfpair_lo(vA.z), acc[4]);
        acc[5] = fmaf(wA, bfpair_hi(vA.z), acc[5]);
        acc[6] = fmaf(wA, bfpair_lo(vA.w), acc[6]);
        acc[7] = fmaf(wA, bfpair_hi(vA.w), acc[7]);
        acc[0] = fmaf(wB, bfpair_lo(vB.x), acc[0]);
        acc[1] = fmaf(wB, bfpair_hi(vB.x), acc[1]);
        acc[2] = fmaf(wB, bfpair_lo(vB.y), acc[2]);
        acc[3] = fmaf(wB, bfpair_hi(vB.y), acc[3]);
        acc[4] = fmaf(wB, bfpair_lo(vB.z), acc[4]);
        acc[5] = fmaf(wB, bfpair_hi(vB.z), acc[5]);
        acc[6] = fmaf(wB, bfpair_lo(vB.w), acc[6]);
        acc[7] = fmaf(wB, bfpair_hi(vB.w), acc[7]);
    }
    // fold slot 1 into slot 0 (same c): +8 within quarter; wsum rides along (head==chunk)
#pragma unroll
    for (int k = 0; k < 8; ++k) acc[k] += __shfl(acc[k], lane + 8, 64);
    wsum_l += __shfl(wsum_l, lane + 8, 64);
    if (g == 0 && dvalid) {
        float inv = 1.f / (wsum_l + 1e-16f);
        float4 bA = *(const float4*)(b1 + 8 * c);
        float4 bB = *(const float4*)(b1 + 8 * c + 4);
        float o[8];
        o[0] = acc[0] * inv + bA.x;
        o[1] = acc[1] * inv + bA.y;
        o[2] = acc[2] * inv + bA.z;
        o[3] = acc[3] * inv + bA.w;
        o[4] = acc[4] * inv + bB.x;
        o[5] = acc[5] * inv + bB.y;
        o[6] = acc[6] * inv + bB.z;
        o[7] = acc[7] * inv + bB.w;
#pragma unroll
        for (int k = 0; k < 8; ++k) o[k] = o[k] > 0.f ? o[k] : (__expf(o[k]) - 1.f);
        float4 s0 = make_float4(o[0], o[1], o[2], o[3]);
        float4 s1 = make_float4(o[4], o[5], o[6], o[7]);
        *(float4*)(y1 + (size_t)d * 64 + 8 * c) = s0;       // fp32 (precision-critical)
        *(float4*)(y1 + (size_t)d * 64 + 8 * c + 4) = s1;
    }
}

// ---------------- Layer 2 GEMM, split-bf16 (y1 replay-variant -> fp32-class needed) ----------
__global__ __launch_bounds__(256) void k_gemm2(const float* __restrict__ y1,
                                               const short* __restrict__ w2h,
                                               const short* __restrict__ w2l,
                                               const float* __restrict__ att_s,
                                               const float* __restrict__ att_d,
                                               unsigned short* __restrict__ h2b,
                                               float* __restrict__ a2s,
                                               float* __restrict__ a2d, int N) {
    int tid = threadIdx.x, wave = tid >> 6, lane = tid & 63;
    int n16 = lane & 15, q = lane >> 4;
    int nb = blockIdx.x * 64 + wave * 16;
    if (nb >= N) return;

    int arow = nb + n16; if (arow >= N) arow = N - 1;
    const float* yr = y1 + (size_t)arow * 64 + q * 8;
    short8 ah[2], al[2];
#pragma unroll
    for (int kc = 0; kc < 2; ++kc) {
        float4 u0 = *(const float4*)(yr + kc * 32);
        float4 u1 = *(const float4*)(yr + kc * 32 + 4);
        short8 h, l; short hi, lo;
        splitbf(u0.x, hi, lo); h[0] = hi; l[0] = lo;
        splitbf(u0.y, hi, lo); h[1] = hi; l[1] = lo;
        splitbf(u0.z, hi, lo); h[2] = hi; l[2] = lo;
        splitbf(u0.w, hi, lo); h[3] = hi; l[3] = lo;
        splitbf(u1.x, hi, lo); h[4] = hi; l[4] = lo;
        splitbf(u1.y, hi, lo); h[5] = hi; l[5] = lo;
        splitbf(u1.z, hi, lo); h[6] = hi; l[6] = lo;
        splitbf(u1.w, hi, lo); h[7] = hi; l[7] = lo;
        ah[kc] = h; al[kc] = l;
    }

    float psr[4] = {0.f, 0.f, 0.f, 0.f}, pdr[4] = {0.f, 0.f, 0.f, 0.f};
#pragma unroll
    for (int ct = 0; ct < 3; ++ct) {
        int n = ct * 16 + n16;
        short8 bh0, bh1, bl0, bl1;
#pragma unroll
        for (int j = 0; j < 8; ++j) {
            int k0 = q * 8 + j;
            bh0[j] = w2h[k0 * 48 + n];
            bl0[j] = w2l[k0 * 48 + n];
            bh1[j] = w2h[(32 + k0) * 48 + n];
            bl1[j] = w2l[(32 + k0) * 48 + n];
        }
        floatx4 c = {0.f, 0.f, 0.f, 0.f};
        c = __builtin_amdgcn_mfma_f32_16x16x32_bf16(ah[0], bl0, c, 0, 0, 0);
        c = __builtin_amdgcn_mfma_f32_16x16x32_bf16(al[0], bh0, c, 0, 0, 0);
        c = __builtin_amdgcn_mfma_f32_16x16x32_bf16(ah[0], bh0, c, 0, 0, 0);
        c = __builtin_amdgcn_mfma_f32_16x16x32_bf16(ah[1], bl1, c, 0, 0, 0);
        c = __builtin_amdgcn_mfma_f32_16x16x32_bf16(al[1], bh1, c, 0, 0, 0);
        c = __builtin_amdgcn_mfma_f32_16x16x32_bf16(ah[1], bh1, c, 0, 0, 0);

        int col = ct * 16 + n16;
#pragma unroll
        for (int r = 0; r < 4; ++r) {
            int row = nb + q * 4 + r;
            if (col < 40 && row < N) h2b[(size_t)row * 40 + col] = (unsigned short)f2bf(c[r]);
        }
        float asv = (col < 40) ? att_s[col] : 0.f;
        float adv = (col < 40) ? att_d[col] : 0.f;
#pragma unroll
        for (int r = 0; r < 4; ++r) {
            psr[r] = fmaf(c[r], asv, psr[r]);
            pdr[r] = fmaf(c[r], adv, pdr[r]);
        }
    }
#pragma unroll
    for (int r = 0; r < 4; ++r) {
        float ps = psr[r], pd = pdr[r];
#pragma unroll
        for (int m = 1; m < 16; m <<= 1) {
            ps += __shfl_xor(ps, m, 64);
            pd += __shfl_xor(pd, m, 64);
        }
        int row = nb + q * 4 + r;
        if (n16 == 0 && row < N) { a2s[row] = ps; a2d[row] = pd; }
    }
}

// ---------------- Layer 2 aggregation: R14 node-per-quarter, shfl-free main loop ------------
// 4 nodes/wave. Quarter q (lanes 16q..16q+15): ll = g*5+c for ll<15 (g=0..2 edge slot,
// c=0..4 16B row chunk), lane 15 idle. Each lane DIRECTLY loads csr_src[i0+j+g] (5-way
// same-address broadcast) and redundantly computes the exp -- redundant per-lane work is
// free wave-instruction-wise. Zero shfls in main loop; epilogue amortized over 4 nodes.
__global__ __launch_bounds__(256) void k_agg2(const unsigned short* __restrict__ h2b,
                                              const float* __restrict__ a2s,
                                              const float* __restrict__ a2d,
                                              const int* __restrict__ offsets,
                                              const int* __restrict__ csr_src,
                                              const float* __restrict__ b2,
                                              float* __restrict__ out, int N) {
    int wave = threadIdx.x >> 6, lane = threadIdx.x & 63;
    int q = lane >> 4;                   // quarter = node slot
    int ll = lane & 15;                  // lane within quarter
    int d = (blockIdx.x * 4 + wave) * 4 + q;
    bool dvalid = (d < N);
    int de = dvalid ? d : N - 1;
    int g = ll / 5;                      // edge slot 0..2 (3 for idle lane 15)
    int c = ll - g * 5;                  // 16B chunk 0..4
    bool lane_ok = (ll < 15);
    float ad = a2d[de];
    float w0 = lrelu_exp(a2s[de] + ad);
    int i0 = offsets[de];
    int deg = offsets[de + 1] - i0;
    if (!dvalid) deg = 0;
    // max degree across the 4 quarters -> uniform loop bound
    int dmax = deg;
    dmax = max(dmax, __shfl_xor(dmax, 16, 64));
    dmax = max(dmax, __shfl_xor(dmax, 32, 64));
    float acc[8] = {0.f, 0.f, 0.f, 0.f, 0.f, 0.f, 0.f, 0.f};
    float wsum_l = 0.f;
    if (g == 0) {                        // self-loop handled by g==0 lanes (ll 0..4)
        uint4 v = *(const uint4*)(h2b + (size_t)de * 40 + 8 * c);
        acc[0] = w0 * bfpair_lo(v.x); acc[1] = w0 * bfpair_hi(v.x);
        acc[2] = w0 * bfpair_lo(v.y); acc[3] = w0 * bfpair_hi(v.y);
        acc[4] = w0 * bfpair_lo(v.z); acc[5] = w0 * bfpair_hi(v.z);
        acc[6] = w0 * bfpair_lo(v.w); acc[7] = w0 * bfpair_hi(v.w);
    }
    for (int j = 0; j < dmax; j += 6) {
        int jA = j + g, jB = j + 3 + g;
        bool liveA = lane_ok && (jA < deg);
        bool liveB = lane_ok && (jB < deg);
        int svA = de, svB = de;
        if (liveA) svA = csr_src[i0 + jA];
        if (liveB) svB = csr_src[i0 + jB];
        float eA = a2s[svA] + ad;
        float eB = a2s[svB] + ad;
        uint4 vA = *(const uint4*)(h2b + (size_t)svA * 40 + 8 * c);
        uint4 vB = *(const uint4*)(h2b + (size_t)svB * 40 + 8 * c);
        float wA = liveA ? lrelu_exp(eA) : 0.f;
        float wB = liveB ? lrelu_exp(eB) : 0.f;
        if (c == 0) wsum_l += wA + wB;   // one counting lane per (quarter, slot)
        acc[0] = fmaf(wA, bfpair_lo(vA.x), acc[0]);
        acc[1] = fmaf(wA, bfpair_hi(vA.x), acc[1]);
        acc[2] = fmaf(wA, bfpair_lo(vA.y), acc[2]);
        acc[3] = fmaf(wA, bfpair_hi(vA.y), acc[3]);
        acc[4] = fmaf(wA, bfpair_lo(vA.z), acc[4]);
        acc[5] = fmaf(wA, bfpair_hi(vA.z), acc[5]);
        acc[6] = fmaf(wA, bfpair_lo(vA.w), acc[6]);
        acc[7] = fmaf(wA, bfpair_hi(vA.w), acc[7]);
        acc[0] = fmaf(wB, bfpair_lo(vB.x), acc[0]);
        acc[1] = fmaf(wB, bfpair_hi(vB.x), acc[1]);
        acc[2] = fmaf(wB, bfpair_lo(vB.y), acc[2]);
        acc[3] = fmaf(wB, bfpair_hi(vB.y), acc[3]);
        acc[4] = fmaf(wB, bfpair_lo(vB.z), acc[4]);
        acc[5] = fmaf(wB, bfpair_hi(vB.z), acc[5]);
        acc[6] = fmaf(wB, bfpair_lo(vB.w), acc[6]);
        acc[7] = fmaf(wB, bfpair_hi(vB.w), acc[7]);
    }
    // fold 3 edge slots into g==0 lanes (same c): +5, +10 within quarter
#pragma unroll
    for (int k = 0; k < 8; ++k)
        acc[k] += __shfl(acc[k], lane + 5, 64) + __shfl(acc[k], lane + 10, 64);
    wsum_l += __shfl(wsum_l, lane + 5, 64) + __shfl(wsum_l, lane + 10, 64);
    wsum_l = __shfl(wsum_l, lane & 48, 64);       // broadcast quarter total (from ll==0)
    float wsum = wsum_l + w0;
    bool act5 = (ll < 5) && dvalid;
    float inv = 1.f / (wsum + 1e-16f);
    float4 bA = *(const float4*)(b2 + 8 * c);
    float4 bB = *(const float4*)(b2 + 8 * c + 4);
    float o[8];
    o[0] = acc[0] * inv + bA.x;
    o[1] = acc[1] * inv + bA.y;
    o[2] = acc[2] * inv + bA.z;
    o[3] = acc[3] * inv + bA.w;
    o[4] = acc[4] * inv + bB.x;
    o[5] = acc[5] * inv + bB.y;
    o[6] = acc[6] * inv + bB.z;
    o[7] = acc[7] * inv + bB.w;
    // log_softmax over 40 ch: ll 0..4 hold 8 each; 3-step butterfly inside 8-lane group
    float mxl = -INFINITY;
    if (act5) {
        mxl = fmaxf(fmaxf(fmaxf(o[0], o[1]), fmaxf(o[2], o[3])),
                    fmaxf(fmaxf(o[4], o[5]), fmaxf(o[6], o[7])));
    }
#pragma unroll
    for (int mm = 1; mm < 8; mm <<= 1) mxl = fmaxf(mxl, __shfl_xor(mxl, mm, 64));
    float exl = 0.f;
    if (act5) {
#pragma unroll
        for (int k = 0; k < 8; ++k) exl += __expf(o[k] - mxl);
    }
#pragma unroll
    for (int mm = 1; mm < 8; mm <<= 1) exl += __shfl_xor(exl, mm, 64);
    if (act5) {
        float lse = mxl + __logf(exl);
        float4 s0 = make_float4(o[0] - lse, o[1] - lse, o[2] - lse, o[3] - lse);
        float4 s1 = make_float4(o[4] - lse, o[5] - lse, o[6] - lse, o[7] - lse);
        *(float4*)(out + (size_t)d * 40 + 8 * c) = s0;
        *(float4*)(out + (size_t)d * 40 + 8 * c + 4) = s1;
    }
}

// ---------------- launcher ----------------

extern "C" void kernel_launch(void* const* d_in, const int* in_sizes, int n_in,
                              void* d_out, int out_size, void* d_ws, size_t ws_size,
                              hipStream_t stream) {
    const float* x   = (const float*)d_in[0];
    const int*   ei  = (const int*)d_in[1];
    const float* W1  = (const float*)d_in[2];
    const float* as1 = (const float*)d_in[3];
    const float* ad1 = (const float*)d_in[4];
    const float* b1  = (const float*)d_in[5];
    const float* W2  = (const float*)d_in[6];
    const float* as2 = (const float*)d_in[7];
    const float* ad2 = (const float*)d_in[8];
    const float* b2  = (const float*)d_in[9];
    float* out = (float*)d_out;

    int N = in_sizes[0] / 128;   // 100000
    int E = in_sizes[1] / 2;     // 1600000
    const int* src = ei;
    const int* dst = ei + E;

    int NBUK = (N + 255) >> BSHIFT;          // 391
    int CHUNK = 4096;
    int NBLK = (E + CHUNK - 1) / CHUNK;      // 391

    char* ws = (char*)d_ws;
    size_t off = 0;
    auto alloc = [&](size_t bytes) -> char* {
        char* p = ws + off;
        off += (bytes + 255) & ~(size_t)255;
        return p;
    };
    unsigned short* h1b = (unsigned short*)alloc((size_t)N * 64 * 2);   // bf16
    float* a_s1    = (float*)alloc((size_t)N * 8 * 4);
    float* a_d1    = (float*)alloc((size_t)N * 8 * 4);
    float* y1      = (float*)alloc((size_t)N * 64 * 4);                 // fp32 (precision-critical)
    // h2b (bf16, 8 MB) and packed (uint, 6.4 MB) are temporally disjoint: share region.
    size_t shared_sz = (size_t)N * 40 * 2;
    if ((size_t)E * 4 > shared_sz) shared_sz = (size_t)E * 4;
    char*  region  = alloc(shared_sz);
    unsigned short* h2b = (unsigned short*)region;
    unsigned* packed    = (unsigned*)region;
    float* a2s     = (float*)alloc((size_t)N * 4);
    float* a2d     = (float*)alloc((size_t)N * 4);
    int*   offsets = (int*)alloc((size_t)(N + 1) * 4);
    int*   csr_src = (int*)alloc((size_t)E * 4);
    int*   blockhist  = (int*)alloc((size_t)NBUK * NBLK * 4);
    int*   btot       = (int*)alloc((size_t)NBUK * 4);
    int*   bucketbase = (int*)alloc((size_t)(NBUK + 1) * 4);
    short* w2h     = (short*)alloc((size_t)64 * 48 * 2);
    short* w2l     = (short*)alloc((size_t)64 * 48 * 2);

    int nb1 = (N + 15) / 16;     // agg1: 16 nodes per block (4 waves x 4 quarters)
    int nb2 = (N + 15) / 16;     // agg2: 16 nodes per block (4 waves x 4 quarters)
    int gb = (N + 63) / 64;

    k_hist<<<NBLK, 512, 0, stream>>>(dst, E, CHUNK, NBLK, NBUK, blockhist);
    k_colscan<<<NBUK, 256, 0, stream>>>(blockhist, btot, NBLK);
    k_bucket_scan<<<1, 512, 0, stream>>>(btot, bucketbase, NBUK);
    k_partition<<<NBLK, 512, 0, stream>>>(src, dst, E, CHUNK, NBLK, NBUK, blockhist,
                                          bucketbase, packed);
    k_fine<<<NBUK, 256, 0, stream>>>(packed, bucketbase, offsets, csr_src, N, NBUK);
    k_splitW2<<<12, 256, 0, stream>>>(W2, w2h, w2l);
    k_gemm1<<<gb, 256, 0, stream>>>(x, W1, as1, ad1, h1b, a_s1, a_d1, N);
    k_agg1<<<nb1, 256, 0, stream>>>(h1b, a_s1, a_d1, offsets, csr_src, b1, y1, N);
    k_gemm2<<<gb, 256, 0, stream>>>(y1, w2h, w2l, as2, ad2, h2b, a2s, a2d, N);
    k_agg2<<<nb2, 256, 0, stream>>>(h2b, a2s, a2d, offsets, csr_src, b2, out, N);
}

// Round 5
// 169.716 us; speedup vs baseline: 1.1357x; 1.0085x over previous
//
#include <hip/hip_runtime.h>
#include <math.h>

#define NEG_SLOPE 0.2f
#define BSHIFT 8            // 256 nodes per bucket
#define MAXBUK 512          // supports N up to 131072

typedef __attribute__((ext_vector_type(8))) short short8;   // 8 bf16 (MFMA A/B frag)
typedef __attribute__((ext_vector_type(4))) float floatx4;  // MFMA C/D frag

static __device__ __forceinline__ float lrelu_exp(float e) {
    e = fmaxf(e, NEG_SLOPE * e);
    return __expf(e);
}

// fp32 -> bf16 (round-to-nearest-even)
static __device__ __forceinline__ short f2bf(float f) {
    union { float f; unsigned u; } v; v.f = f;
    unsigned r = v.u + 0x7FFFu + ((v.u >> 16) & 1u);
    return (short)(r >> 16);
}
// bf16 bits -> fp32 (exact)
static __device__ __forceinline__ float bf2f(unsigned short s) {
    union { float f; unsigned u; } v;
    v.u = ((unsigned)s) << 16;
    return v.f;
}
// packed pair of bf16 -> two fp32 (1 shift / 1 and)
static __device__ __forceinline__ float bfpair_lo(unsigned v) {
    union { float f; unsigned u; } x; x.u = v << 16; return x.f;
}
static __device__ __forceinline__ float bfpair_hi(unsigned v) {
    union { float f; unsigned u; } x; x.u = v & 0xffff0000u; return x.f;
}
// split f into hi+lo bf16 pair (covers ~16 mantissa bits)
static __device__ __forceinline__ void splitbf(float f, short& hi, short& lo) {
    hi = f2bf(f);
    lo = f2bf(f - bf2f((unsigned short)hi));
}

// ================= CSR build: LDS-bucketed partition (no global data atomics) =================

__global__ __launch_bounds__(512) void k_hist(const int* __restrict__ dst, int E, int CHUNK,
                                              int NBLK, int NBUK, int* __restrict__ blockhist) {
    __shared__ int hist[MAXBUK];
    int t = threadIdx.x, b = blockIdx.x;
    for (int i = t; i < NBUK; i += 512) hist[i] = 0;
    __syncthreads();
    int e0 = b * CHUNK, e1 = e0 + CHUNK; if (e1 > E) e1 = E;
    for (int e = e0 + t; e < e1; e += 512) atomicAdd(&hist[dst[e] >> BSHIFT], 1);
    __syncthreads();
    for (int i = t; i < NBUK; i += 512) blockhist[(size_t)i * NBLK + b] = hist[i];
}

// Per-bucket LOCAL exclusive scan across NBLK block-counts (carry loop), writes bucket total.
__global__ __launch_bounds__(256) void k_colscan(int* __restrict__ blockhist,
                                                 int* __restrict__ btot, int NBLK) {
    int bucket = blockIdx.x, t = threadIdx.x;
    int lane = t & 63, wv = t >> 6;
    __shared__ int wsum[4];
    __shared__ int carry_s;
    if (t == 0) carry_s = 0;
    __syncthreads();
    for (int base = 0; base < NBLK; base += 256) {
        int idx = base + t;
        int v = (idx < NBLK) ? blockhist[(size_t)bucket * NBLK + idx] : 0;
        int s = v;
#pragma unroll
        for (int o = 1; o < 64; o <<= 1) {
            int u = __shfl_up(s, o, 64);
            if (lane >= o) s += u;
        }
        if (lane == 63) wsum[wv] = s;
        __syncthreads();
        int b0 = 0;
#pragma unroll
        for (int w = 0; w < 4; ++w) b0 += (w < wv) ? wsum[w] : 0;
        int excl = s + b0 - v + carry_s;
        if (idx < NBLK) blockhist[(size_t)bucket * NBLK + idx] = excl;
        __syncthreads();
        if (t == 255) carry_s += s + b0;   // chunk total
        __syncthreads();
    }
    if (t == 0) btot[bucket] = carry_s;
}

// Exclusive scan over NBUK bucket totals (NBUK <= 512).
__global__ __launch_bounds__(512) void k_bucket_scan(const int* __restrict__ btot,
                                                     int* __restrict__ bucketbase, int NBUK) {
    __shared__ int sh[512];
    int t = threadIdx.x;
    int v = (t < NBUK) ? btot[t] : 0;
    sh[t] = v;
    __syncthreads();
#pragma unroll
    for (int o = 1; o < 512; o <<= 1) {
        int u = (t >= o) ? sh[t - o] : 0;
        __syncthreads();
        sh[t] += u;
        __syncthreads();
    }
    if (t < NBUK) bucketbase[t] = sh[t] - v;
    if (t == NBUK - 1) bucketbase[NBUK] = sh[t];
}

// packed record: (src << 8) | (dst & 255)   [src < 2^24; bucket id recovers dst high bits]
__global__ __launch_bounds__(512) void k_partition(const int* __restrict__ src,
                                                   const int* __restrict__ dst, int E, int CHUNK,
                                                   int NBLK, int NBUK,
                                                   const int* __restrict__ blockhist,
                                                   const int* __restrict__ bucketbase,
                                                   unsigned* __restrict__ packed) {
    __shared__ int cur[MAXBUK];
    int t = threadIdx.x, b = blockIdx.x;
    for (int i = t; i < NBUK; i += 512)
        cur[i] = blockhist[(size_t)i * NBLK + b] + bucketbase[i];
    __syncthreads();
    int e0 = b * CHUNK, e1 = e0 + CHUNK; if (e1 > E) e1 = E;
    for (int e = e0 + t; e < e1; e += 512) {
        int d = dst[e], s = src[e];
        int pos = atomicAdd(&cur[d >> BSHIFT], 1);
        packed[pos] = ((unsigned)s << 8) | ((unsigned)d & 255u);
    }
}

__global__ __launch_bounds__(256) void k_fine(const unsigned* __restrict__ packed,
                                              const int* __restrict__ bucketbase,
                                              int* __restrict__ offsets,
                                              int* __restrict__ csr_src,
                                              int N, int NBUK) {
    __shared__ int fcnt[256];
    __shared__ int wsum[4];
    int bucket = blockIdx.x, t = threadIdx.x;
    int lo = bucket << BSHIFT;
    int nn = N - lo; if (nn > 256) nn = 256;
    int ebase = bucketbase[bucket];
    int ecnt = bucketbase[bucket + 1] - ebase;
    fcnt[t] = 0;
    __syncthreads();
    for (int i = t; i < ecnt; i += 256) {
        unsigned p = packed[ebase + i];
        atomicAdd(&fcnt[p & 255u], 1);
    }
    __syncthreads();
    int v = fcnt[t];
    int lane = t & 63, wv = t >> 6;
    int s = v;
#pragma unroll
    for (int o = 1; o < 64; o <<= 1) {
        int u = __shfl_up(s, o, 64);
        if (lane >= o) s += u;
    }
    if (lane == 63) wsum[wv] = s;
    __syncthreads();
    int base = 0;
#pragma unroll
    for (int w = 0; w < 4; ++w) base += (w < wv) ? wsum[w] : 0;
    int excl = s + base - v;
    if (t < nn) offsets[lo + t] = ebase + excl;
    if (bucket == NBUK - 1 && t == 0) offsets[N] = ebase + ecnt;  // == E
    __syncthreads();
    fcnt[t] = excl;   // reuse as cursor
    __syncthreads();
    for (int i = t; i < ecnt; i += 256) {
        unsigned p = packed[ebase + i];
        int pos = atomicAdd(&fcnt[p & 255u], 1);
        csr_src[ebase + pos] = (int)(p >> 8);
    }
}

// ---------------- W2 pre-split: hi/lo bf16, padded 40 -> 48 cols ----------------
__global__ __launch_bounds__(256) void k_splitW2(const float* __restrict__ W2,
                                                 short* __restrict__ w2h,
                                                 short* __restrict__ w2l) {
    int i = blockIdx.x * 256 + threadIdx.x;
    if (i < 64 * 48) {
        int row = i / 48, col = i % 48;
        short hi = 0, lo = 0;
        if (col < 40) splitbf(W2[row * 40 + col], hi, lo);
        w2h[i] = hi; w2l[i] = lo;
    }
}

// ---------------- Layer 1 GEMM via MFMA bf16 (plain; inputs replay-constant) ----------------
__global__ __launch_bounds__(256) void k_gemm1(const float* __restrict__ x,
                                               const float* __restrict__ W1,
                                               const float* __restrict__ att_s,
                                               const float* __restrict__ att_d,
                                               unsigned short* __restrict__ h1b,
                                               float* __restrict__ a_s1,
                                               float* __restrict__ a_d1, int N) {
    int tid = threadIdx.x, wave = tid >> 6, lane = tid & 63;
    int n16 = lane & 15, q = lane >> 4;
    int nb = blockIdx.x * 64 + wave * 16;
    if (nb >= N) return;

    short8 bfr[4][4];
#pragma unroll
    for (int ct = 0; ct < 4; ++ct) {
        int n = ct * 16 + n16;
#pragma unroll
        for (int kc = 0; kc < 4; ++kc) {
            int k0 = kc * 32 + q * 8;
            short8 b;
#pragma unroll
            for (int j = 0; j < 8; ++j) b[j] = f2bf(W1[(k0 + j) * 64 + n]);
            bfr[ct][kc] = b;
        }
    }

    int arow = nb + n16; if (arow >= N) arow = N - 1;
    const float* xr = x + (size_t)arow * 128 + q * 8;
    short8 afr[4];
#pragma unroll
    for (int kc = 0; kc < 4; ++kc) {
        float4 u0 = *(const float4*)(xr + kc * 32);
        float4 u1 = *(const float4*)(xr + kc * 32 + 4);
        short8 a;
        a[0] = f2bf(u0.x); a[1] = f2bf(u0.y); a[2] = f2bf(u0.z); a[3] = f2bf(u0.w);
        a[4] = f2bf(u1.x); a[5] = f2bf(u1.y); a[6] = f2bf(u1.z); a[7] = f2bf(u1.w);
        afr[kc] = a;
    }

    floatx4 acc[4];
#pragma unroll
    for (int ct = 0; ct < 4; ++ct) {
        floatx4 c = {0.f, 0.f, 0.f, 0.f};
#pragma unroll
        for (int kc = 0; kc < 4; ++kc)
            c = __builtin_amdgcn_mfma_f32_16x16x32_bf16(afr[kc], bfr[ct][kc], c, 0, 0, 0);
        acc[ct] = c;
    }

#pragma unroll
    for (int ct = 0; ct < 4; ++ct) {
#pragma unroll
        for (int r = 0; r < 4; ++r) {
            int row = nb + q * 4 + r;
            if (row < N) h1b[(size_t)row * 64 + ct * 16 + n16] = (unsigned short)f2bf(acc[ct][r]);
        }
    }

#pragma unroll
    for (int ct = 0; ct < 4; ++ct) {
        float as = att_s[ct * 16 + n16];
        float ad = att_d[ct * 16 + n16];
#pragma unroll
        for (int r = 0; r < 4; ++r) {
            float ps = acc[ct][r] * as;
            float pd = acc[ct][r] * ad;
#pragma unroll
            for (int m = 1; m < 8; m <<= 1) {
                ps += __shfl_xor(ps, m, 64);
                pd += __shfl_xor(pd, m, 64);
            }
            int row = nb + q * 4 + r;
            if ((n16 & 7) == 0 && row < N) {
                int h = 2 * ct + (n16 >> 3);
                a_s1[row * 8 + h] = ps;
                a_d1[row * 8 + h] = pd;
            }
        }
    }
}

// ---------------- Layer 1 aggregation: R16 node-per-quarter + 4-deep gather batching --------
// 4 nodes/wave. Quarter: g = ll>>3 slot (0..1), c = ll&7 chunk==head. Per iteration each lane
// loads 4 contiguous edge indices (independent dword loads), then issues ALL 8 dependent
// gathers (4 a_s1 + 4 h1b uint4) as one group: 2 memory epochs per 8 edges (was 4), 9 loads
// in flight per lane (was 3) -> hides gather latency (R15 was latency-bound: VALUBusy 34%).
__global__ __launch_bounds__(256) void k_agg1(const unsigned short* __restrict__ h1b,
                                              const float* __restrict__ a_s1,
                                              const float* __restrict__ a_d1,
                                              const int* __restrict__ offsets,
                                              const int* __restrict__ csr_src,
                                              const float* __restrict__ b1,
                                              float* __restrict__ y1, int N) {
    int wave = threadIdx.x >> 6, lane = threadIdx.x & 63;
    int q = lane >> 4;                   // quarter = node slot
    int ll = lane & 15;                  // lane within quarter
    int d = (blockIdx.x * 4 + wave) * 4 + q;
    bool dvalid = (d < N);
    int de = dvalid ? d : N - 1;
    int g = ll >> 3;                     // edge slot 0..1
    int c = ll & 7;                      // chunk == head
    float ad = a_d1[de * 8 + c];
    int i0 = offsets[de];
    int deg = dvalid ? (offsets[de + 1] - i0) : 0;
    // max degree across the 4 quarters -> uniform loop bound
    int dmax = deg;
    dmax = max(dmax, __shfl_xor(dmax, 16, 64));
    dmax = max(dmax, __shfl_xor(dmax, 32, 64));
    float acc[8] = {0.f, 0.f, 0.f, 0.f, 0.f, 0.f, 0.f, 0.f};
    float wsum_l = 0.f;
    if (g == 0) {                        // self-loop on slot 0
        float w0 = lrelu_exp(a_s1[de * 8 + c] + ad);
        uint4 v = *(const uint4*)(h1b + (size_t)de * 64 + 8 * c);
        acc[0] = w0 * bfpair_lo(v.x); acc[1] = w0 * bfpair_hi(v.x);
        acc[2] = w0 * bfpair_lo(v.y); acc[3] = w0 * bfpair_hi(v.y);
        acc[4] = w0 * bfpair_lo(v.z); acc[5] = w0 * bfpair_hi(v.z);
        acc[6] = w0 * bfpair_lo(v.w); acc[7] = w0 * bfpair_hi(v.w);
        wsum_l = w0;
    }
    for (int j = 0; j < dmax; j += 8) {
        int b0 = i0 + j + 4 * g;
        int idx[4]; bool lv[4];
#pragma unroll
        for (int u = 0; u < 4; ++u) {
            int jj = j + 4 * g + u;
            lv[u] = (jj < deg);
            idx[u] = de;
            if (lv[u]) idx[u] = csr_src[b0 + u];
        }
        float ev[4];
#pragma unroll
        for (int u = 0; u < 4; ++u) ev[u] = a_s1[idx[u] * 8 + c] + ad;
        uint4 vv[4];
#pragma unroll
        for (int u = 0; u < 4; ++u)
            vv[u] = *(const uint4*)(h1b + (size_t)idx[u] * 64 + 8 * c);
#pragma unroll
        for (int u = 0; u < 4; ++u) {
            float w = lv[u] ? lrelu_exp(ev[u]) : 0.f;
            wsum_l += w;
            acc[0] = fmaf(w, bfpair_lo(vv[u].x), acc[0]);
            acc[1] = fmaf(w, bfpair_hi(vv[u].x), acc[1]);
            acc[2] = fmaf(w, bfpair_lo(vv[u].y), acc[2]);
            acc[3] = fmaf(w, bfpair_hi(vv[u].y), acc[3]);
            acc[4] = fmaf(w, bfpair_lo(vv[u].z), acc[4]);
            acc[5] = fmaf(w, bfpair_hi(vv[u].z), acc[5]);
            acc[6] = fmaf(w, bfpair_lo(vv[u].w), acc[6]);
            acc[7] = fmaf(w, bfpair_hi(vv[u].w), acc[7]);
        }
    }
    // fold slot 1 into slot 0 (same c): +8 within quarter; wsum rides along (head==chunk)
#pragma unroll
    for (int k = 0; k < 8; ++k) acc[k] += __shfl(acc[k], lane + 8, 64);
    wsum_l += __shfl(wsum_l, lane + 8, 64);
    if (g == 0 && dvalid) {
        float inv = 1.f / (wsum_l + 1e-16f);
        float4 bA = *(const float4*)(b1 + 8 * c);
        float4 bB = *(const float4*)(b1 + 8 * c + 4);
        float o[8];
        o[0] = acc[0] * inv + bA.x;
        o[1] = acc[1] * inv + bA.y;
        o[2] = acc[2] * inv + bA.z;
        o[3] = acc[3] * inv + bA.w;
        o[4] = acc[4] * inv + bB.x;
        o[5] = acc[5] * inv + bB.y;
        o[6] = acc[6] * inv + bB.z;
        o[7] = acc[7] * inv + bB.w;
#pragma unroll
        for (int k = 0; k < 8; ++k) o[k] = o[k] > 0.f ? o[k] : (__expf(o[k]) - 1.f);
        float4 s0 = make_float4(o[0], o[1], o[2], o[3]);
        float4 s1 = make_float4(o[4], o[5], o[6], o[7]);
        *(float4*)(y1 + (size_t)d * 64 + 8 * c) = s0;       // fp32 (precision-critical)
        *(float4*)(y1 + (size_t)d * 64 + 8 * c + 4) = s1;
    }
}

// ---------------- Layer 2 GEMM, split-bf16 (y1 replay-variant -> fp32-class needed) ----------
__global__ __launch_bounds__(256) void k_gemm2(const float* __restrict__ y1,
                                               const short* __restrict__ w2h,
                                               const short* __restrict__ w2l,
                                               const float* __restrict__ att_s,
                                               const float* __restrict__ att_d,
                                               unsigned short* __restrict__ h2b,
                                               float* __restrict__ a2s,
                                               float* __restrict__ a2d, int N) {
    int tid = threadIdx.x, wave = tid >> 6, lane = tid & 63;
    int n16 = lane & 15, q = lane >> 4;
    int nb = blockIdx.x * 64 + wave * 16;
    if (nb >= N) return;

    int arow = nb + n16; if (arow >= N) arow = N - 1;
    const float* yr = y1 + (size_t)arow * 64 + q * 8;
    short8 ah[2], al[2];
#pragma unroll
    for (int kc = 0; kc < 2; ++kc) {
        float4 u0 = *(const float4*)(yr + kc * 32);
        float4 u1 = *(const float4*)(yr + kc * 32 + 4);
        short8 h, l; short hi, lo;
        splitbf(u0.x, hi, lo); h[0] = hi; l[0] = lo;
        splitbf(u0.y, hi, lo); h[1] = hi; l[1] = lo;
        splitbf(u0.z, hi, lo); h[2] = hi; l[2] = lo;
        splitbf(u0.w, hi, lo); h[3] = hi; l[3] = lo;
        splitbf(u1.x, hi, lo); h[4] = hi; l[4] = lo;
        splitbf(u1.y, hi, lo); h[5] = hi; l[5] = lo;
        splitbf(u1.z, hi, lo); h[6] = hi; l[6] = lo;
        splitbf(u1.w, hi, lo); h[7] = hi; l[7] = lo;
        ah[kc] = h; al[kc] = l;
    }

    float psr[4] = {0.f, 0.f, 0.f, 0.f}, pdr[4] = {0.f, 0.f, 0.f, 0.f};
#pragma unroll
    for (int ct = 0; ct < 3; ++ct) {
        int n = ct * 16 + n16;
        short8 bh0, bh1, bl0, bl1;
#pragma unroll
        for (int j = 0; j < 8; ++j) {
            int k0 = q * 8 + j;
            bh0[j] = w2h[k0 * 48 + n];
            bl0[j] = w2l[k0 * 48 + n];
            bh1[j] = w2h[(32 + k0) * 48 + n];
            bl1[j] = w2l[(32 + k0) * 48 + n];
        }
        floatx4 c = {0.f, 0.f, 0.f, 0.f};
        c = __builtin_amdgcn_mfma_f32_16x16x32_bf16(ah[0], bl0, c, 0, 0, 0);
        c = __builtin_amdgcn_mfma_f32_16x16x32_bf16(al[0], bh0, c, 0, 0, 0);
        c = __builtin_amdgcn_mfma_f32_16x16x32_bf16(ah[0], bh0, c, 0, 0, 0);
        c = __builtin_amdgcn_mfma_f32_16x16x32_bf16(ah[1], bl1, c, 0, 0, 0);
        c = __builtin_amdgcn_mfma_f32_16x16x32_bf16(al[1], bh1, c, 0, 0, 0);
        c = __builtin_amdgcn_mfma_f32_16x16x32_bf16(ah[1], bh1, c, 0, 0, 0);

        int col = ct * 16 + n16;
#pragma unroll
        for (int r = 0; r < 4; ++r) {
            int row = nb + q * 4 + r;
            if (col < 40 && row < N) h2b[(size_t)row * 40 + col] = (unsigned short)f2bf(c[r]);
        }
        float asv = (col < 40) ? att_s[col] : 0.f;
        float adv = (col < 40) ? att_d[col] : 0.f;
#pragma unroll
        for (int r = 0; r < 4; ++r) {
            psr[r] = fmaf(c[r], asv, psr[r]);
            pdr[r] = fmaf(c[r], adv, pdr[r]);
        }
    }
#pragma unroll
    for (int r = 0; r < 4; ++r) {
        float ps = psr[r], pd = pdr[r];
#pragma unroll
        for (int m = 1; m < 16; m <<= 1) {
            ps += __shfl_xor(ps, m, 64);
            pd += __shfl_xor(pd, m, 64);
        }
        int row = nb + q * 4 + r;
        if (n16 == 0 && row < N) { a2s[row] = ps; a2d[row] = pd; }
    }
}

// ---------------- Layer 2 aggregation: R16 node-per-quarter + 4-deep gather batching --------
// Quarter: g = ll/5 slot (0..2), c = ll%5 chunk, lane 15 idle. Each lane batches 4 edge
// indices then 8 dependent gathers -> 12 edges/quarter/iter, 2 memory epochs (was 4).
__global__ __launch_bounds__(256) void k_agg2(const unsigned short* __restrict__ h2b,
                                              const float* __restrict__ a2s,
                                              const float* __restrict__ a2d,
                                              const int* __restrict__ offsets,
                                              const int* __restrict__ csr_src,
                                              const float* __restrict__ b2,
                                              float* __restrict__ out, int N) {
    int wave = threadIdx.x >> 6, lane = threadIdx.x & 63;
    int q = lane >> 4;                   // quarter = node slot
    int ll = lane & 15;                  // lane within quarter
    int d = (blockIdx.x * 4 + wave) * 4 + q;
    bool dvalid = (d < N);
    int de = dvalid ? d : N - 1;
    int g = ll / 5;                      // edge slot 0..2 (3 for idle lane 15)
    int c = ll - g * 5;                  // 16B chunk 0..4
    bool lane_ok = (ll < 15);
    float ad = a2d[de];
    float w0 = lrelu_exp(a2s[de] + ad);
    int i0 = offsets[de];
    int deg = offsets[de + 1] - i0;
    if (!dvalid) deg = 0;
    // max degree across the 4 quarters -> uniform loop bound
    int dmax = deg;
    dmax = max(dmax, __shfl_xor(dmax, 16, 64));
    dmax = max(dmax, __shfl_xor(dmax, 32, 64));
    float acc[8] = {0.f, 0.f, 0.f, 0.f, 0.f, 0.f, 0.f, 0.f};
    float wsum_l = 0.f;
    if (g == 0) {                        // self-loop handled by g==0 lanes (ll 0..4)
        uint4 v = *(const uint4*)(h2b + (size_t)de * 40 + 8 * c);
        acc[0] = w0 * bfpair_lo(v.x); acc[1] = w0 * bfpair_hi(v.x);
        acc[2] = w0 * bfpair_lo(v.y); acc[3] = w0 * bfpair_hi(v.y);
        acc[4] = w0 * bfpair_lo(v.z); acc[5] = w0 * bfpair_hi(v.z);
        acc[6] = w0 * bfpair_lo(v.w); acc[7] = w0 * bfpair_hi(v.w);
    }
    for (int j = 0; j < dmax; j += 12) {
        int b0 = i0 + j + 4 * g;
        int idx[4]; bool lv[4];
#pragma unroll
        for (int u = 0; u < 4; ++u) {
            int jj = j + 4 * g + u;
            lv[u] = lane_ok && (jj < deg);
            idx[u] = de;
            if (lv[u]) idx[u] = csr_src[b0 + u];
        }
        float ev[4];
#pragma unroll
        for (int u = 0; u < 4; ++u) ev[u] = a2s[idx[u]] + ad;
        uint4 vv[4];
#pragma unroll
        for (int u = 0; u < 4; ++u)
            vv[u] = *(const uint4*)(h2b + (size_t)idx[u] * 40 + 8 * c);
#pragma unroll
        for (int u = 0; u < 4; ++u) {
            float w = lv[u] ? lrelu_exp(ev[u]) : 0.f;
            if (c == 0) wsum_l += w;     // one counting lane per (quarter, slot)
            acc[0] = fmaf(w, bfpair_lo(vv[u].x), acc[0]);
            acc[1] = fmaf(w, bfpair_hi(vv[u].x), acc[1]);
            acc[2] = fmaf(w, bfpair_lo(vv[u].y), acc[2]);
            acc[3] = fmaf(w, bfpair_hi(vv[u].y), acc[3]);
            acc[4] = fmaf(w, bfpair_lo(vv[u].z), acc[4]);
            acc[5] = fmaf(w, bfpair_hi(vv[u].z), acc[5]);
            acc[6] = fmaf(w, bfpair_lo(vv[u].w), acc[6]);
            acc[7] = fmaf(w, bfpair_hi(vv[u].w), acc[7]);
        }
    }
    // fold 3 edge slots into g==0 lanes (same c): +5, +10 within quarter
#pragma unroll
    for (int k = 0; k < 8; ++k)
        acc[k] += __shfl(acc[k], lane + 5, 64) + __shfl(acc[k], lane + 10, 64);
    wsum_l += __shfl(wsum_l, lane + 5, 64) + __shfl(wsum_l, lane + 10, 64);
    wsum_l = __shfl(wsum_l, lane & 48, 64);       // broadcast quarter total (from ll==0)
    float wsum = wsum_l + w0;
    bool act5 = (ll < 5) && dvalid;
    float inv = 1.f / (wsum + 1e-16f);
    float4 bA = *(const float4*)(b2 + 8 * c);
    float4 bB = *(const float4*)(b2 + 8 * c + 4);
    float o[8];
    o[0] = acc[0] * inv + bA.x;
    o[1] = acc[1] * inv + bA.y;
    o[2] = acc[2] * inv + bA.z;
    o[3] = acc[3] * inv + bA.w;
    o[4] = acc[4] * inv + bB.x;
    o[5] = acc[5] * inv + bB.y;
    o[6] = acc[6] * inv + bB.z;
    o[7] = acc[7] * inv + bB.w;
    // log_softmax over 40 ch: ll 0..4 hold 8 each; 3-step butterfly inside 8-lane group
    float mxl = -INFINITY;
    if (act5) {
        mxl = fmaxf(fmaxf(fmaxf(o[0], o[1]), fmaxf(o[2], o[3])),
                    fmaxf(fmaxf(o[4], o[5]), fmaxf(o[6], o[7])));
    }
#pragma unroll
    for (int mm = 1; mm < 8; mm <<= 1) mxl = fmaxf(mxl, __shfl_xor(mxl, mm, 64));
    float exl = 0.f;
    if (act5) {
#pragma unroll
        for (int k = 0; k < 8; ++k) exl += __expf(o[k] - mxl);
    }
#pragma unroll
    for (int mm = 1; mm < 8; mm <<= 1) exl += __shfl_xor(exl, mm, 64);
    if (act5) {
        float lse = mxl + __logf(exl);
        float4 s0 = make_float4(o[0] - lse, o[1] - lse, o[2] - lse, o[3] - lse);
        float4 s1 = make_float4(o[4] - lse, o[5] - lse, o[6] - lse, o[7] - lse);
        *(float4*)(out + (size_t)d * 40 + 8 * c) = s0;
        *(float4*)(out + (size_t)d * 40 + 8 * c + 4) = s1;
    }
}

// ---------------- launcher ----------------

extern "C" void kernel_launch(void* const* d_in, const int* in_sizes, int n_in,
                              void* d_out, int out_size, void* d_ws, size_t ws_size,
                              hipStream_t stream) {
    const float* x   = (const float*)d_in[0];
    const int*   ei  = (const int*)d_in[1];
    const float* W1  = (const float*)d_in[2];
    const float* as1 = (const float*)d_in[3];
    const float* ad1 = (const float*)d_in[4];
    const float* b1  = (const float*)d_in[5];
    const float* W2  = (const float*)d_in[6];
    const float* as2 = (const float*)d_in[7];
    const float* ad2 = (const float*)d_in[8];
    const float* b2  = (const float*)d_in[9];
    float* out = (float*)d_out;

    int N = in_sizes[0] / 128;   // 100000
    int E = in_sizes[1] / 2;     // 1600000
    const int* src = ei;
    const int* dst = ei + E;

    int NBUK = (N + 255) >> BSHIFT;          // 391
    int CHUNK = 4096;
    int NBLK = (E + CHUNK - 1) / CHUNK;      // 391

    char* ws = (char*)d_ws;
    size_t off = 0;
    auto alloc = [&](size_t bytes) -> char* {
        char* p = ws + off;
        off += (bytes + 255) & ~(size_t)255;
        return p;
    };
    unsigned short* h1b = (unsigned short*)alloc((size_t)N * 64 * 2);   // bf16
    float* a_s1    = (float*)alloc((size_t)N * 8 * 4);
    float* a_d1    = (float*)alloc((size_t)N * 8 * 4);
    float* y1      = (float*)alloc((size_t)N * 64 * 4);                 // fp32 (precision-critical)
    // h2b (bf16, 8 MB) and packed (uint, 6.4 MB) are temporally disjoint: share region.
    size_t shared_sz = (size_t)N * 40 * 2;
    if ((size_t)E * 4 > shared_sz) shared_sz = (size_t)E * 4;
    char*  region  = alloc(shared_sz);
    unsigned short* h2b = (unsigned short*)region;
    unsigned* packed    = (unsigned*)region;
    float* a2s     = (float*)alloc((size_t)N * 4);
    float* a2d     = (float*)alloc((size_t)N * 4);
    int*   offsets = (int*)alloc((size_t)(N + 1) * 4);
    int*   csr_src = (int*)alloc((size_t)E * 4);
    int*   blockhist  = (int*)alloc((size_t)NBUK * NBLK * 4);
    int*   btot       = (int*)alloc((size_t)NBUK * 4);
    int*   bucketbase = (int*)alloc((size_t)(NBUK + 1) * 4);
    short* w2h     = (short*)alloc((size_t)64 * 48 * 2);
    short* w2l     = (short*)alloc((size_t)64 * 48 * 2);

    int nb1 = (N + 15) / 16;     // agg1: 16 nodes per block (4 waves x 4 quarters)
    int nb2 = (N + 15) / 16;     // agg2: 16 nodes per block (4 waves x 4 quarters)
    int gb = (N + 63) / 64;

    k_hist<<<NBLK, 512, 0, stream>>>(dst, E, CHUNK, NBLK, NBUK, blockhist);
    k_colscan<<<NBUK, 256, 0, stream>>>(blockhist, btot, NBLK);
    k_bucket_scan<<<1, 512, 0, stream>>>(btot, bucketbase, NBUK);
    k_partition<<<NBLK, 512, 0, stream>>>(src, dst, E, CHUNK, NBLK, NBUK, blockhist,
                                          bucketbase, packed);
    k_fine<<<NBUK, 256, 0, stream>>>(packed, bucketbase, offsets, csr_src, N, NBUK);
    k_splitW2<<<12, 256, 0, stream>>>(W2, w2h, w2l);
    k_gemm1<<<gb, 256, 0, stream>>>(x, W1, as1, ad1, h1b, a_s1, a_d1, N);
    k_agg1<<<nb1, 256, 0, stream>>>(h1b, a_s1, a_d1, offsets, csr_src, b1, y1, N);
    k_gemm2<<<gb, 256, 0, stream>>>(y1, w2h, w2l, as2, ad2, h2b, a2s, a2d, N);
    k_agg2<<<nb2, 256, 0, stream>>>(h2b, a2s, a2d, offsets, csr_src, b2, out, N);
}